// Round 1
// baseline (459.769 us; speedup 1.0000x reference)
//
#include <hip/hip_runtime.h>

#define HID 32
#define CC  64
#define TT  8
#define NN  1024
#define BB  4
#define KTOT (TT*NN)   // 8192

// ---------------- K1a: h_q[b,n,d] = sum_c w_q[d,c] * h[b,c,n] ----------------
__global__ __launch_bounds__(256) void k_hq(const float* __restrict__ h,
                                            const float* __restrict__ wq,
                                            float* __restrict__ hq) {
    int gid = blockIdx.x * 256 + threadIdx.x;      // 0..4095  (b,n)
    int b = gid >> 10, n = gid & 1023;
    float acc[HID];
#pragma unroll
    for (int d = 0; d < HID; d++) acc[d] = 0.f;
    const float* hb = h + (b * CC) * NN + n;
    for (int c = 0; c < CC; c++) {
        float v = hb[c * NN];                      // coalesced across lanes (n fastest)
#pragma unroll
        for (int d = 0; d < HID; d++) acc[d] += wq[d * CC + c] * v;  // wq uniform -> s_load
    }
    float4* o = (float4*)(hq + (size_t)gid * HID);
#pragma unroll
    for (int d4 = 0; d4 < 8; d4++) {
        float4 v; v.x = acc[d4*4+0]; v.y = acc[d4*4+1]; v.z = acc[d4*4+2]; v.w = acc[d4*4+3];
        o[d4] = v;
    }
}

// ------------- K1b: H_kv[b,d,t,n] = sum_c w_kv[d,c] * H[b,c,t,n] -------------
__global__ __launch_bounds__(256) void k_hkv(const float* __restrict__ H,
                                             const float* __restrict__ wkv,
                                             float* __restrict__ hkv) {
    int gid = blockIdx.x * 256 + threadIdx.x;      // 0..32767 (b,t,n)
    int b = gid >> 13, t = (gid >> 10) & 7, n = gid & 1023;
    float acc[HID];
#pragma unroll
    for (int d = 0; d < HID; d++) acc[d] = 0.f;
    const float* Hb = H + ((size_t)(b * CC) * TT + t) * NN + n;
    for (int c = 0; c < CC; c++) {
        float v = Hb[(size_t)c * TT * NN];         // coalesced across lanes
#pragma unroll
        for (int d = 0; d < HID; d++) acc[d] += wkv[d * CC + c] * v;
    }
    float* o = hkv + (size_t)(b * HID) * KTOT + t * NN + n;
#pragma unroll
    for (int d = 0; d < HID; d++) o[(size_t)d * KTOT] = acc[d];  // coalesced across lanes per d
}

// ---- K2: scores + softmax(axis=k) + att write. One block per (b,m) column ----
__global__ __launch_bounds__(256) void k_att(const float* __restrict__ hq,
                                             const float* __restrict__ hkv,
                                             float* __restrict__ att) {
    int hw = blockIdx.x;                           // 0..4095
    int logical = (hw & 7) * 512 + (hw >> 3);      // XCD swizzle: consecutive m on same XCD
    int b = logical >> 10, m = logical & 1023;
    int tid = threadIdx.x;

    __shared__ float col[TT][HID];                 // H_kv column for this m
    __shared__ float red[4];

    {
        int d = tid & 31, t = tid >> 5;            // 256 threads cover 8x32
        col[t][d] = hkv[(size_t)(b * HID + d) * KTOT + t * NN + m];
    }
    __syncthreads();

    float s[4][TT];
    float mx = -3.0e38f;
    const float* hqb = hq + ((size_t)b << 10) * HID;

    // process n-rows in 2 groups of 2 to bound VGPR pressure
#pragma unroll
    for (int g = 0; g < 2; g++) {
        float qr[2][HID];
#pragma unroll
        for (int j = 0; j < 2; j++) {
            int n = (g * 2 + j) * 256 + tid;
            const float4* p = (const float4*)(hqb + (size_t)n * HID);
#pragma unroll
            for (int d4 = 0; d4 < 8; d4++) {
                float4 v = p[d4];
                qr[j][d4*4+0] = v.x; qr[j][d4*4+1] = v.y;
                qr[j][d4*4+2] = v.z; qr[j][d4*4+3] = v.w;
            }
        }
#pragma unroll
        for (int t = 0; t < TT; t++) {
            float cr[HID];
            const float4* cp = (const float4*)(&col[t][0]);
#pragma unroll
            for (int d4 = 0; d4 < 8; d4++) {
                float4 v = cp[d4];
                cr[d4*4+0] = v.x; cr[d4*4+1] = v.y; cr[d4*4+2] = v.z; cr[d4*4+3] = v.w;
            }
#pragma unroll
            for (int j = 0; j < 2; j++) {
                float acc = 0.f;
#pragma unroll
                for (int d = 0; d < HID; d++) acc += qr[j][d] * cr[d];
                int nn = g * 2 + j;
                int n = nn * 256 + tid;
                if (n == m) acc = 0.f;             // diagonal removal
                s[nn][t] = acc;
                mx = fmaxf(mx, acc);
            }
        }
    }

    // block-reduce max
#pragma unroll
    for (int off = 32; off >= 1; off >>= 1) mx = fmaxf(mx, __shfl_xor(mx, off, 64));
    int wave = tid >> 6, lane = tid & 63;
    if (lane == 0) red[wave] = mx;
    __syncthreads();
    mx = fmaxf(fmaxf(red[0], red[1]), fmaxf(red[2], red[3]));
    __syncthreads();

    float sum = 0.f;
#pragma unroll
    for (int nn = 0; nn < 4; nn++)
#pragma unroll
        for (int t = 0; t < TT; t++) {
            float e = __expf(s[nn][t] - mx);
            s[nn][t] = e;
            sum += e;
        }
#pragma unroll
    for (int off = 32; off >= 1; off >>= 1) sum += __shfl_xor(sum, off, 64);
    if (lane == 0) red[wave] = sum;
    __syncthreads();
    sum = red[0] + red[1] + red[2] + red[3];
    float inv = 1.0f / sum;

    float* ab = att + (size_t)(b * KTOT) * NN + m;
#pragma unroll
    for (int t = 0; t < TT; t++)
#pragma unroll
        for (int nn = 0; nn < 4; nn++) {
            int k = t * NN + nn * 256 + tid;
            ab[(size_t)k * NN] = s[nn][t] * inv;
        }
}

// -------- K3: h_v partials. hvp[b,kc,d,m] = sum_{k in chunk} H_kv[b,d,k]*att[b,k,m] --------
__global__ __launch_bounds__(256) void k_hv(const float* __restrict__ att,
                                            const float* __restrict__ hkv,
                                            float* __restrict__ hvp) {
    int bx = blockIdx.x;                           // 0..511
    int b = bx >> 7, r = bx & 127, mt = r >> 5, kc = r & 31;
    int m = mt * 256 + threadIdx.x;
    int k0 = kc * 256;
    float acc[HID];
#pragma unroll
    for (int d = 0; d < HID; d++) acc[d] = 0.f;
    const float* ab = att + ((size_t)b * KTOT + k0) * NN + m;
    const float* hk = hkv + (size_t)b * HID * KTOT + k0;   // wave-uniform -> scalar loads
    for (int kk4 = 0; kk4 < 64; kk4++) {
        float a0 = ab[(size_t)(kk4*4+0) * NN];
        float a1 = ab[(size_t)(kk4*4+1) * NN];
        float a2 = ab[(size_t)(kk4*4+2) * NN];
        float a3 = ab[(size_t)(kk4*4+3) * NN];
#pragma unroll
        for (int d = 0; d < HID; d++) {
            float4 h4 = *(const float4*)(hk + (size_t)d * KTOT + kk4 * 4);
            acc[d] += h4.x * a0 + h4.y * a1 + h4.z * a2 + h4.w * a3;
        }
    }
    float* o = hvp + (size_t)((b * 32 + kc) * HID) * NN + m;
#pragma unroll
    for (int d = 0; d < HID; d++) o[(size_t)d * NN] = acc[d];   // coalesced per d
}

// -------- K4: out0[b,c,m] = h[b,c,m] + sum_d w_o[c,d] * sum_kc hvp[b,kc,d,m] --------
__global__ __launch_bounds__(256) void k_out(const float* __restrict__ h,
                                             const float* __restrict__ wo,
                                             const float* __restrict__ hvp,
                                             float* __restrict__ out0) {
    int bx = blockIdx.x;                           // 0..127
    int b = bx >> 5, mt = bx & 31;
    int m0 = mt * 32;
    int tid = threadIdx.x;
    __shared__ float hvL[HID][32];
    for (int i = tid; i < HID * 32; i += 256) {
        int d = i >> 5, mm = i & 31;
        float s = 0.f;
        for (int kc = 0; kc < 32; kc++)
            s += hvp[(size_t)((b * 32 + kc) * HID + d) * NN + m0 + mm];
        hvL[d][mm] = s;
    }
    __syncthreads();
    for (int i = tid; i < CC * 32; i += 256) {
        int c = i >> 5, mm = i & 31;
        float v = h[(size_t)(b * CC + c) * NN + m0 + mm];
#pragma unroll
        for (int d = 0; d < HID; d++) v += wo[c * HID + d] * hvL[d][mm];
        out0[(size_t)(b * CC + c) * NN + m0 + mm] = v;
    }
}

extern "C" void kernel_launch(void* const* d_in, const int* in_sizes, int n_in,
                              void* d_out, int out_size, void* d_ws, size_t ws_size,
                              hipStream_t stream) {
    const float* H   = (const float*)d_in[0];
    const float* h   = (const float*)d_in[1];
    const float* wq  = (const float*)d_in[2];
    const float* wkv = (const float*)d_in[3];
    const float* wo  = (const float*)d_in[4];

    float* out0 = (float*)d_out;                       // [4,64,32,32]
    float* att  = out0 + (size_t)BB * CC * NN;         // [4,8192,1024]

    float* ws  = (float*)d_ws;
    float* hq  = ws;                                   // 4*1024*32      = 131072
    float* hkv = ws + 131072;                          // 4*32*8192     = 1048576
    float* hvp = ws + 131072 + 1048576;                // 4*32*32*1024  = 4194304

    k_hq <<<16,   256, 0, stream>>>(h, wq, hq);
    k_hkv<<<128,  256, 0, stream>>>(H, wkv, hkv);
    k_att<<<4096, 256, 0, stream>>>(hq, hkv, att);
    k_hv <<<512,  256, 0, stream>>>(att, hkv, hvp);
    k_out<<<128,  256, 0, stream>>>(h, wo, hvp, out0);
}

// Round 2
// 272.203 us; speedup vs baseline: 1.6891x; 1.6891x over previous
//
#include <hip/hip_runtime.h>

#define HID 32
#define CC  64
#define TT  8
#define NN  1024
#define BB  4
#define KTOT (TT*NN)   // 8192
#define NCH 32         // n-chunks for k_sum / k_att2
#define CH  (NN/NCH)   // 32 n per chunk

// ---------------- K1a: h_q[b,n,d] = sum_c w_q[d,c] * h[b,c,n] ----------------
__global__ __launch_bounds__(256) void k_hq(const float* __restrict__ h,
                                            const float* __restrict__ wq,
                                            float* __restrict__ hq) {
    int gid = blockIdx.x * 256 + threadIdx.x;      // 0..4095  (b,n)
    int b = gid >> 10, n = gid & 1023;
    float acc[HID];
#pragma unroll
    for (int d = 0; d < HID; d++) acc[d] = 0.f;
    const float* hb = h + (b * CC) * NN + n;
    for (int c = 0; c < CC; c++) {
        float v = hb[c * NN];                      // coalesced across lanes (n fastest)
#pragma unroll
        for (int d = 0; d < HID; d++) acc[d] += wq[d * CC + c] * v;  // wq uniform -> s_load
    }
    float4* o = (float4*)(hq + (size_t)gid * HID);
#pragma unroll
    for (int d4 = 0; d4 < 8; d4++) {
        float4 v; v.x = acc[d4*4+0]; v.y = acc[d4*4+1]; v.z = acc[d4*4+2]; v.w = acc[d4*4+3];
        o[d4] = v;
    }
}

// --- K1b: H_kv[b,d,k] (d-major) AND hkvT[b,k,d] (k-major) from H, w_kv ---
__global__ __launch_bounds__(256) void k_hkv(const float* __restrict__ H,
                                             const float* __restrict__ wkv,
                                             float* __restrict__ hkv,
                                             float* __restrict__ hkvT) {
    int gid = blockIdx.x * 256 + threadIdx.x;      // 0..32767 (b,t,n)
    int b = gid >> 13, t = (gid >> 10) & 7, n = gid & 1023;
    float acc[HID];
#pragma unroll
    for (int d = 0; d < HID; d++) acc[d] = 0.f;
    const float* Hb = H + ((size_t)(b * CC) * TT + t) * NN + n;
    for (int c = 0; c < CC; c++) {
        float v = Hb[(size_t)c * TT * NN];         // coalesced across lanes
#pragma unroll
        for (int d = 0; d < HID; d++) acc[d] += wkv[d * CC + c] * v;
    }
    float* o = hkv + (size_t)(b * HID) * KTOT + t * NN + n;
#pragma unroll
    for (int d = 0; d < HID; d++) o[(size_t)d * KTOT] = acc[d];  // coalesced per d
    float4* o2 = (float4*)(hkvT + ((size_t)(b * KTOT) + t * NN + n) * HID);
#pragma unroll
    for (int d4 = 0; d4 < 8; d4++) {
        float4 v; v.x = acc[d4*4+0]; v.y = acc[d4*4+1]; v.z = acc[d4*4+2]; v.w = acc[d4*4+3];
        o2[d4] = v;
    }
}

// ---- K2a: partial softmax denominators. psum[b][nc][m] = sum over chunk's k of exp(score) ----
// score(k=(t,n), m) = dot_d hq[b,n,d] * hkv[b,d,t*NN+m];  diagonal (n==m) -> score 0
__global__ __launch_bounds__(256) void k_sum(const float* __restrict__ hq,
                                             const float* __restrict__ hkv,
                                             float* __restrict__ psum) {
    int bx = blockIdx.x;                           // 512 blocks: b(4) x mt(4) x nc(32)
    int b = bx >> 7, r = bx & 127, mt = r >> 5, nc = r & 31;
    int m = mt * 256 + threadIdx.x;
    int nbase = nc * CH;
    const float* hqb  = hq  + ((size_t)b << 10) * HID;
    const float* hkb  = hkv + (size_t)b * HID * KTOT;
    float sum = 0.f;
    for (int t = 0; t < TT; t++) {
        float cr[HID];
#pragma unroll
        for (int d = 0; d < HID; d++) cr[d] = hkb[(size_t)d * KTOT + t * NN + m]; // coalesced
#pragma unroll 2
        for (int n0 = 0; n0 < CH; n0++) {
            int n = nbase + n0;
            const float* hqr = hqb + (size_t)n * HID;   // wave-uniform -> s_load
            float s0 = 0.f, s1 = 0.f, s2 = 0.f, s3 = 0.f;
#pragma unroll
            for (int d = 0; d < 8; d++) {
                s0 += cr[d]      * hqr[d];
                s1 += cr[d + 8]  * hqr[d + 8];
                s2 += cr[d + 16] * hqr[d + 16];
                s3 += cr[d + 24] * hqr[d + 24];
            }
            float sc = (s0 + s1) + (s2 + s3);
            if (n == m) sc = 0.f;                  // removed diagonal -> exp(0)=1
            sum += __expf(sc);
        }
    }
    psum[((size_t)(b * NCH + nc) << 10) + m] = sum;    // coalesced
}

// ---- K3: recompute scores, write normalized att (coalesced), fuse h_v partials ----
__global__ __launch_bounds__(256) void k_att2(const float* __restrict__ hq,
                                              const float* __restrict__ hkv,
                                              const float* __restrict__ hkvT,
                                              const float* __restrict__ psum,
                                              float* __restrict__ att,
                                              float* __restrict__ hvp) {
    int bx = blockIdx.x;                           // 512 blocks: b(4) x mt(4) x nc(32)
    int b = bx >> 7, r = bx & 127, mt = r >> 5, nc = r & 31;
    int m = mt * 256 + threadIdx.x;
    int nbase = nc * CH;

    // total denominator for this (b,m)
    float gsum = 0.f;
#pragma unroll
    for (int j = 0; j < NCH; j++)
        gsum += psum[((size_t)(b * NCH + j) << 10) + m];   // coalesced
    float inv = 1.0f / gsum;

    const float* hqb = hq   + ((size_t)b << 10) * HID;
    const float* hkb = hkv  + (size_t)b * HID * KTOT;
    const float* htb = hkvT + (size_t)b * KTOT * HID;
    float* ab = att + (size_t)b * KTOT * NN + m;

    float acc[HID];
#pragma unroll
    for (int d = 0; d < HID; d++) acc[d] = 0.f;

    for (int t = 0; t < TT; t++) {
        float cr[HID];
#pragma unroll
        for (int d = 0; d < HID; d++) cr[d] = hkb[(size_t)d * KTOT + t * NN + m]; // coalesced
#pragma unroll 2
        for (int n0 = 0; n0 < CH; n0++) {
            int n = nbase + n0;
            const float* hqr = hqb + (size_t)n * HID;      // wave-uniform -> s_load
            float s0 = 0.f, s1 = 0.f, s2 = 0.f, s3 = 0.f;
#pragma unroll
            for (int d = 0; d < 8; d++) {
                s0 += cr[d]      * hqr[d];
                s1 += cr[d + 8]  * hqr[d + 8];
                s2 += cr[d + 16] * hqr[d + 16];
                s3 += cr[d + 24] * hqr[d + 24];
            }
            float sc = (s0 + s1) + (s2 + s3);
            if (n == m) sc = 0.f;
            float a = __expf(sc) * inv;
            ab[(size_t)(t * NN + n) * NN] = a;             // coalesced 4B/lane
            const float* hvr = htb + (size_t)(t * NN + n) * HID;  // wave-uniform -> s_load
#pragma unroll
            for (int d = 0; d < HID; d++) acc[d] += a * hvr[d];
        }
    }
    // hvp[b][nc][d][m]
    float* o = hvp + (size_t)((b * NCH + nc) * HID) * NN + m;
#pragma unroll
    for (int d = 0; d < HID; d++) o[(size_t)d * NN] = acc[d];   // coalesced per d
}

// -------- K4: out0[b,c,m] = h[b,c,m] + sum_d w_o[c,d] * sum_nc hvp[b,nc,d,m] --------
__global__ __launch_bounds__(256) void k_out(const float* __restrict__ h,
                                             const float* __restrict__ wo,
                                             const float* __restrict__ hvp,
                                             float* __restrict__ out0) {
    int bx = blockIdx.x;                           // 0..127
    int b = bx >> 5, mt = bx & 31;
    int m0 = mt * 32;
    int tid = threadIdx.x;
    __shared__ float hvL[HID][32];
    for (int i = tid; i < HID * 32; i += 256) {
        int d = i >> 5, mm = i & 31;
        float s = 0.f;
        for (int kc = 0; kc < NCH; kc++)
            s += hvp[(size_t)((b * NCH + kc) * HID + d) * NN + m0 + mm];
        hvL[d][mm] = s;
    }
    __syncthreads();
    for (int i = tid; i < CC * 32; i += 256) {
        int c = i >> 5, mm = i & 31;
        float v = h[(size_t)(b * CC + c) * NN + m0 + mm];
#pragma unroll
        for (int d = 0; d < HID; d++) v += wo[c * HID + d] * hvL[d][mm];
        out0[(size_t)(b * CC + c) * NN + m0 + mm] = v;
    }
}

extern "C" void kernel_launch(void* const* d_in, const int* in_sizes, int n_in,
                              void* d_out, int out_size, void* d_ws, size_t ws_size,
                              hipStream_t stream) {
    const float* H   = (const float*)d_in[0];
    const float* h   = (const float*)d_in[1];
    const float* wq  = (const float*)d_in[2];
    const float* wkv = (const float*)d_in[3];
    const float* wo  = (const float*)d_in[4];

    float* out0 = (float*)d_out;                       // [4,64,32,32]
    float* att  = out0 + (size_t)BB * CC * NN;         // [4,8192,1024]

    float* ws   = (float*)d_ws;
    float* hq   = ws;                                  // 131072
    float* hkv  = hq   + 131072;                       // 1048576
    float* hkvT = hkv  + 1048576;                      // 1048576
    float* psum = hkvT + 1048576;                      // 131072
    float* hvp  = psum + 131072;                       // 4194304  (tot 26.2 MB)

    k_hq  <<<16,  256, 0, stream>>>(h, wq, hq);
    k_hkv <<<128, 256, 0, stream>>>(H, wkv, hkv, hkvT);
    k_sum <<<512, 256, 0, stream>>>(hq, hkv, psum);
    k_att2<<<512, 256, 0, stream>>>(hq, hkv, hkvT, psum, att, hvp);
    k_out <<<128, 256, 0, stream>>>(h, wo, hvp, out0);
}

// Round 3
// 244.354 us; speedup vs baseline: 1.8816x; 1.1140x over previous
//
#include <hip/hip_runtime.h>

#define HID 32
#define CC  64
#define TT  8
#define NN  1024
#define BB  4
#define KTOT (TT*NN)   // 8192
#define NCH 64         // k-chunks (over n) for k_sum / k_att2
#define LOGN 6
#define CH  (NN/NCH)   // 16 n per chunk

// ---------------- K1a: h_q[b,n,d] = sum_c w_q[d,c] * h[b,c,n] ----------------
__global__ __launch_bounds__(256) void k_hq(const float* __restrict__ h,
                                            const float* __restrict__ wq,
                                            float* __restrict__ hq) {
    int gid = blockIdx.x * 256 + threadIdx.x;      // 0..4095  (b,n)
    int b = gid >> 10;
    float acc[HID];
#pragma unroll
    for (int d = 0; d < HID; d++) acc[d] = 0.f;
    const float* hb = h + (size_t)(b * CC) * NN + (gid & 1023);
    for (int c = 0; c < CC; c++) {
        float v = hb[c * NN];                      // coalesced across lanes
#pragma unroll
        for (int d = 0; d < HID; d++) acc[d] += wq[d * CC + c] * v;  // uniform -> s_load
    }
    float4* o = (float4*)(hq + (size_t)gid * HID);
#pragma unroll
    for (int d4 = 0; d4 < 8; d4++) {
        float4 v; v.x = acc[d4*4+0]; v.y = acc[d4*4+1]; v.z = acc[d4*4+2]; v.w = acc[d4*4+3];
        o[d4] = v;
    }
}

// --- K1b: hkvT[b,k,d] (k-major) from H, w_kv ---
__global__ __launch_bounds__(256) void k_hkv(const float* __restrict__ H,
                                             const float* __restrict__ wkv,
                                             float* __restrict__ hkvT) {
    int gid = blockIdx.x * 256 + threadIdx.x;      // 0..32767 (b,t,n)
    int b = gid >> 13;
    int tn = gid & 8191;
    float acc[HID];
#pragma unroll
    for (int d = 0; d < HID; d++) acc[d] = 0.f;
    const float* Hb = H + (size_t)(b * CC) * KTOT + tn;
    for (int c = 0; c < CC; c++) {
        float v = Hb[(size_t)c * KTOT];            // coalesced across lanes
#pragma unroll
        for (int d = 0; d < HID; d++) acc[d] += wkv[d * CC + c] * v;
    }
    float4* o = (float4*)(hkvT + ((size_t)b * KTOT + tn) * HID);
#pragma unroll
    for (int d4 = 0; d4 < 8; d4++) {
        float4 v; v.x = acc[d4*4+0]; v.y = acc[d4*4+1]; v.z = acc[d4*4+2]; v.w = acc[d4*4+3];
        o[d4] = v;
    }
}

// ---- K2: partial softmax denominators. psum[b][nc][m] over the chunk's (t,n) ----
// score(k=(t,n), m) = dot_d hq[b,n,d] * hkvT[b, t*NN+m, d];  diagonal (n==m) -> 0
__global__ __launch_bounds__(256) void k_sum(const float* __restrict__ hq,
                                             const float* __restrict__ hkvT,
                                             float* __restrict__ psum) {
    int bx = blockIdx.x;                           // 1024 blocks: b(4) x mt(4) x nc(64)
    int b = bx >> (2 + LOGN);
    int r = bx & ((4 << LOGN) - 1);
    int mt = r >> LOGN, nc = r & (NCH - 1);
    int m = mt * 256 + threadIdx.x;
    int nbase = nc * CH;

    __shared__ float qs[CH][HID];
    for (int i = threadIdx.x; i < CH * HID; i += 256)
        qs[i >> 5][i & 31] = hq[((size_t)(b << 10) + nbase + (i >> 5)) * HID + (i & 31)];
    __syncthreads();

    const float* htb = hkvT + (size_t)b * KTOT * HID;
    float sum = 0.f;
    for (int t = 0; t < TT; t++) {
        float cr[HID];
        const float4* cp = (const float4*)(htb + (size_t)(t * NN + m) * HID);
#pragma unroll
        for (int d4 = 0; d4 < 8; d4++) {
            float4 v = cp[d4];
            cr[4*d4] = v.x; cr[4*d4+1] = v.y; cr[4*d4+2] = v.z; cr[4*d4+3] = v.w;
        }
#pragma unroll 4
        for (int n0 = 0; n0 < CH; n0++) {
            float s0 = 0.f, s1 = 0.f, s2 = 0.f, s3 = 0.f;
#pragma unroll
            for (int d = 0; d < 8; d++) {
                s0 += cr[d]      * qs[n0][d];
                s1 += cr[d + 8]  * qs[n0][d + 8];
                s2 += cr[d + 16] * qs[n0][d + 16];
                s3 += cr[d + 24] * qs[n0][d + 24];
            }
            float sc = (s0 + s1) + (s2 + s3);
            if (nbase + n0 == m) sc = 0.f;
            sum += __expf(sc);
        }
    }
    psum[((size_t)((b << LOGN) + nc) << 10) + m] = sum;   // coalesced
}

// ---- K3: recompute scores, write normalized att (coalesced), fused hv partials ----
__global__ __launch_bounds__(256) void k_att2(const float* __restrict__ hq,
                                              const float* __restrict__ hkvT,
                                              const float* __restrict__ psum,
                                              float* __restrict__ att,
                                              float* __restrict__ hvp) {
    int bx = blockIdx.x;                           // 1024 blocks: b(4) x mt(4) x nc(64)
    int b = bx >> (2 + LOGN);
    int r = bx & ((4 << LOGN) - 1);
    int mt = r >> LOGN, nc = r & (NCH - 1);
    int m = mt * 256 + threadIdx.x;
    int nbase = nc * CH;

    __shared__ float qs[CH][HID];                  // hq rows of this n-chunk
    __shared__ float vs[TT][CH][HID];              // hkvT rows for k=(t, chunk n)
    for (int i = threadIdx.x; i < CH * HID; i += 256)
        qs[i >> 5][i & 31] = hq[((size_t)(b << 10) + nbase + (i >> 5)) * HID + (i & 31)];
    for (int i = threadIdx.x; i < TT * CH * HID; i += 256) {
        int t = i >> 9, n0 = (i >> 5) & (CH - 1), d = i & 31;
        vs[t][n0][d] = hkvT[((size_t)b * KTOT + t * NN + nbase + n0) * HID + d];
    }
    __syncthreads();

    float gsum = 0.f;
#pragma unroll
    for (int j = 0; j < NCH; j++)
        gsum += psum[((size_t)((b << LOGN) + j) << 10) + m];   // coalesced
    float inv = 1.0f / gsum;

    const float* htb = hkvT + (size_t)b * KTOT * HID;
    float* ab = att + (size_t)b * KTOT * NN + m;

    float acc[HID];
#pragma unroll
    for (int d = 0; d < HID; d++) acc[d] = 0.f;

    for (int t = 0; t < TT; t++) {
        float cr[HID];
        const float4* cp = (const float4*)(htb + (size_t)(t * NN + m) * HID);
#pragma unroll
        for (int d4 = 0; d4 < 8; d4++) {
            float4 v = cp[d4];
            cr[4*d4] = v.x; cr[4*d4+1] = v.y; cr[4*d4+2] = v.z; cr[4*d4+3] = v.w;
        }
#pragma unroll 2
        for (int n0 = 0; n0 < CH; n0++) {
            float s0 = 0.f, s1 = 0.f, s2 = 0.f, s3 = 0.f;
#pragma unroll
            for (int d = 0; d < 8; d++) {
                s0 += cr[d]      * qs[n0][d];
                s1 += cr[d + 8]  * qs[n0][d + 8];
                s2 += cr[d + 16] * qs[n0][d + 16];
                s3 += cr[d + 24] * qs[n0][d + 24];
            }
            float sc = (s0 + s1) + (s2 + s3);
            if (nbase + n0 == m) sc = 0.f;
            float a = __expf(sc) * inv;
            ab[(size_t)(t * NN + nbase + n0) * NN] = a;        // coalesced 4B/lane
#pragma unroll
            for (int d = 0; d < HID; d++) acc[d] += a * vs[t][n0][d];
        }
    }
    // hvp[b][d][nc][m]
    float* o = hvp + ((((size_t)(b * HID)) * NCH + nc) << 10) + m;
#pragma unroll
    for (int d = 0; d < HID; d++) o[((size_t)d * NCH) << 10] = acc[d];  // coalesced per d
}

// -------- K4a: hv[b][d][m] = sum_nc hvp[b][d][nc][m] --------
__global__ __launch_bounds__(256) void k_red(const float* __restrict__ hvp,
                                             float* __restrict__ hv) {
    int bx = blockIdx.x;                           // 512 blocks: b(4) x d(32) x mt(4)
    int b = bx >> 7, r = bx & 127, d = r >> 2, mt = r & 3;
    int m = mt * 256 + threadIdx.x;
    const float* p = hvp + ((((size_t)(b * HID + d)) * NCH) << 10) + m;
    float s = 0.f;
#pragma unroll 8
    for (int nc = 0; nc < NCH; nc++) s += p[(size_t)nc << 10];   // coalesced
    hv[((size_t)(b * HID + d) << 10) + m] = s;
}

// -------- K4b: out0[b,c,m] = h[b,c,m] + sum_d w_o[c,d] * hv[b,d,m] --------
__global__ __launch_bounds__(256) void k_out(const float* __restrict__ h,
                                             const float* __restrict__ wo,
                                             const float* __restrict__ hv,
                                             float* __restrict__ out0) {
    int bx = blockIdx.x;                           // 0..127
    int b = bx >> 5, mt = bx & 31;
    int m0 = mt * 32;
    int tid = threadIdx.x;
    __shared__ float hvL[HID][32];
    for (int i = tid; i < HID * 32; i += 256) {
        int d = i >> 5, mm = i & 31;
        hvL[d][mm] = hv[((size_t)(b * HID + d) << 10) + m0 + mm];
    }
    __syncthreads();
    for (int i = tid; i < CC * 32; i += 256) {
        int c = i >> 5, mm = i & 31;
        float v = h[(size_t)(b * CC + c) * NN + m0 + mm];
#pragma unroll
        for (int d = 0; d < HID; d++) v += wo[c * HID + d] * hvL[d][mm];
        out0[(size_t)(b * CC + c) * NN + m0 + mm] = v;
    }
}

extern "C" void kernel_launch(void* const* d_in, const int* in_sizes, int n_in,
                              void* d_out, int out_size, void* d_ws, size_t ws_size,
                              hipStream_t stream) {
    const float* H   = (const float*)d_in[0];
    const float* h   = (const float*)d_in[1];
    const float* wq  = (const float*)d_in[2];
    const float* wkv = (const float*)d_in[3];
    const float* wo  = (const float*)d_in[4];

    float* out0 = (float*)d_out;                       // [4,64,32,32]
    float* att  = out0 + (size_t)BB * CC * NN;         // [4,8192,1024]

    float* ws   = (float*)d_ws;
    float* hq   = ws;                                  // 131072
    float* hkvT = hq   + 131072;                       // 1048576
    float* psum = hkvT + 1048576;                      // 262144
    float* hvp  = psum + 262144;                       // 8388608
    float* hv   = hvp  + 8388608;                      // 131072   (~40 MB total)

    k_hq  <<<16,   256, 0, stream>>>(h, wq, hq);
    k_hkv <<<128,  256, 0, stream>>>(H, wkv, hkvT);
    k_sum <<<1024, 256, 0, stream>>>(hq, hkvT, psum);
    k_att2<<<1024, 256, 0, stream>>>(hq, hkvT, psum, att, hvp);
    k_red <<<512,  256, 0, stream>>>(hvp, hv);
    k_out <<<128,  256, 0, stream>>>(h, wo, hv, out0);
}

// Round 5
// 122.459 us; speedup vs baseline: 3.7545x; 1.9954x over previous
//
#include <hip/hip_runtime.h>

typedef short bf16x8 __attribute__((ext_vector_type(8)));
typedef float f32x4  __attribute__((ext_vector_type(4)));

#define HID 32
#define CC  64
#define TT  8
#define NN  1024
#define BB  4
#define KTOT 8192
#define NKC 16                 // k-chunks; KCHUNK=512 divides NN -> single t per chunk
#define KCHUNK (KTOT/NKC)      // 512

// f32 -> bf16 (RNE)
__device__ __forceinline__ unsigned short f2b(float x) {
    unsigned int u = __float_as_uint(x);
    return (unsigned short)((u + 0x7fffu + ((u >> 16) & 1u)) >> 16);
}
__device__ __forceinline__ float b2f(unsigned short u) {
    return __uint_as_float((unsigned int)u << 16);
}

// ---------------- K1a: h_q[b,n,d] hi/lo bf16 split ----------------
__global__ __launch_bounds__(256) void k_hq(const float* __restrict__ h,
                                            const float* __restrict__ wq,
                                            unsigned short* __restrict__ hqHI,
                                            unsigned short* __restrict__ hqLO) {
    int gid = blockIdx.x * 256 + threadIdx.x;      // 0..4095  (b,n)
    int b = gid >> 10;
    float acc[HID];
#pragma unroll
    for (int d = 0; d < HID; d++) acc[d] = 0.f;
    const float* hb = h + (size_t)(b * CC) * NN + (gid & 1023);
    for (int c = 0; c < CC; c++) {
        float v = hb[c * NN];                      // coalesced
#pragma unroll
        for (int d = 0; d < HID; d++) acc[d] += wq[d * CC + c] * v;  // uniform -> s_load
    }
    bf16x8* ohi = (bf16x8*)(hqHI + (size_t)gid * HID);
    bf16x8* olo = (bf16x8*)(hqLO + (size_t)gid * HID);
#pragma unroll
    for (int v8 = 0; v8 < 4; v8++) {
        bf16x8 thi, tlo;
#pragma unroll
        for (int j = 0; j < 8; j++) {
            float x = acc[v8 * 8 + j];
            unsigned short hi = f2b(x);
            thi[j] = (short)hi;
            tlo[j] = (short)f2b(x - b2f(hi));
        }
        ohi[v8] = thi; olo[v8] = tlo;
    }
}

// --- K1b: hkT hi/lo (k-major, for score B-frag) AND hkDB (d-major bf16, for V) ---
__global__ __launch_bounds__(256) void k_hkv(const float* __restrict__ H,
                                             const float* __restrict__ wkv,
                                             unsigned short* __restrict__ hkTHI,
                                             unsigned short* __restrict__ hkTLO,
                                             unsigned short* __restrict__ hkDB) {
    int gid = blockIdx.x * 256 + threadIdx.x;      // 0..32767 (b, k=t*NN+n)
    int b = gid >> 13, tn = gid & 8191;
    float acc[HID];
#pragma unroll
    for (int d = 0; d < HID; d++) acc[d] = 0.f;
    const float* Hb = H + (size_t)(b * CC) * KTOT + tn;
    for (int c = 0; c < CC; c++) {
        float v = Hb[(size_t)c * KTOT];            // coalesced
#pragma unroll
        for (int d = 0; d < HID; d++) acc[d] += wkv[d * CC + c] * v;
    }
    unsigned short thi[HID], tlo[HID];
#pragma unroll
    for (int d = 0; d < HID; d++) {
        unsigned short hi = f2b(acc[d]);
        thi[d] = hi;
        tlo[d] = f2b(acc[d] - b2f(hi));
    }
    bf16x8* ohi = (bf16x8*)(hkTHI + ((size_t)b * KTOT + tn) * HID);
    bf16x8* olo = (bf16x8*)(hkTLO + ((size_t)b * KTOT + tn) * HID);
#pragma unroll
    for (int v8 = 0; v8 < 4; v8++) {
        bf16x8 a, l;
#pragma unroll
        for (int j = 0; j < 8; j++) { a[j] = (short)thi[v8*8+j]; l[j] = (short)tlo[v8*8+j]; }
        ohi[v8] = a; olo[v8] = l;
    }
#pragma unroll
    for (int d = 0; d < HID; d++)
        hkDB[((size_t)(b * HID) + d) * KTOT + tn] = thi[d];   // coalesced per d
}

// ---- Pass A: psum[b][kc][m] = sum over chunk rows k=(t,n) of exp(score) ----
// score[k=(t,n)][m] = dot_d hq[n,d] * hkT[t*NN+m, d];  diag (n==m) -> 0
__global__ __launch_bounds__(256) void k_psum(const unsigned short* __restrict__ hqHI,
                                              const unsigned short* __restrict__ hqLO,
                                              const unsigned short* __restrict__ hkTHI,
                                              const unsigned short* __restrict__ hkTLO,
                                              float* __restrict__ psum) {
    int bx = blockIdx.x;                           // 1024: b(4) x mt(16) x kc(16)
    int b = bx >> 8, mt = (bx >> 4) & 15, kc = bx & 15;
    int wave = threadIdx.x >> 6, lane = threadIdx.x & 63;
    int g = lane >> 4, c = lane & 15;
    int m = mt * 64 + wave * 16 + c;
    int t = kc >> 1;
    int nb0 = (kc & 1) << 9;                       // chunk covers n in [nb0, nb0+512)

    // B frag: key column = hkT[t,m] (block-constant), hi/lo
    size_t bqo = ((size_t)b * KTOT + t * NN + m) * HID + 8 * g;
    bf16x8 bqh = *(const bf16x8*)(hkTHI + bqo);
    bf16x8 bql = *(const bf16x8*)(hkTLO + bqo);

    const unsigned short* qhi = hqHI + ((size_t)(b << 10)) * HID;
    const unsigned short* qlo = hqLO + ((size_t)(b << 10)) * HID;

    float csum = 0.f;
    for (int s16 = 0; s16 < KCHUNK / 16; s16++) {  // 32 row-tiles
        int nb = nb0 + s16 * 16;
        size_t ao = (size_t)(nb + c) * HID + 8 * g;
        bf16x8 ah = *(const bf16x8*)(qhi + ao);    // A row = query n = nb+c
        bf16x8 al = *(const bf16x8*)(qlo + ao);
        f32x4 sv = __builtin_amdgcn_mfma_f32_16x16x32_bf16(ah, bql, (f32x4){0.f,0.f,0.f,0.f}, 0, 0, 0);
        sv = __builtin_amdgcn_mfma_f32_16x16x32_bf16(al, bqh, sv, 0, 0, 0);
        sv = __builtin_amdgcn_mfma_f32_16x16x32_bf16(ah, bqh, sv, 0, 0, 0);
        int nrow = nb + 4 * g;                     // D row = query n
#pragma unroll
        for (int r = 0; r < 4; r++) {
            float x = (nrow + r == m) ? 0.f : sv[r];
            csum += __expf(x);
        }
    }
    csum += __shfl_xor(csum, 16);
    csum += __shfl_xor(csum, 32);
    if (lane < 16)
        psum[(((size_t)(b * NKC + kc)) << 10) + mt * 64 + wave * 16 + lane] = csum;
}

// ---- inv[b][m] = 1 / sum_kc psum ----
__global__ __launch_bounds__(256) void k_inv(const float* __restrict__ psum,
                                             float* __restrict__ inv) {
    int gid = blockIdx.x * 256 + threadIdx.x;      // 4096 (b,m)
    int b = gid >> 10, m = gid & 1023;
    float s = 0.f;
#pragma unroll
    for (int kc = 0; kc < NKC; kc++)
        s += psum[(((size_t)(b * NKC + kc)) << 10) + m];
    inv[gid] = 1.0f / s;
}

// ---- Pass B: att (coalesced) + fused hv partials ----
__global__ __launch_bounds__(256) void k_att2(const unsigned short* __restrict__ hqHI,
                                              const unsigned short* __restrict__ hqLO,
                                              const unsigned short* __restrict__ hkTHI,
                                              const unsigned short* __restrict__ hkTLO,
                                              const unsigned short* __restrict__ hkDB,
                                              const float* __restrict__ inv,
                                              float* __restrict__ att,
                                              float* __restrict__ hvp) {
    int bx = blockIdx.x;                           // 1024: b(4) x mt(16) x kc(16)
    int b = bx >> 8, mt = (bx >> 4) & 15, kc = bx & 15;
    int wave = threadIdx.x >> 6, lane = threadIdx.x & 63;
    int g = lane >> 4, c = lane & 15;
    int m = mt * 64 + wave * 16 + c;
    int t = kc >> 1;
    int nb0 = (kc & 1) << 9;

    size_t bqo = ((size_t)b * KTOT + t * NN + m) * HID + 8 * g;
    bf16x8 bqh = *(const bf16x8*)(hkTHI + bqo);
    bf16x8 bql = *(const bf16x8*)(hkTLO + bqo);
    float vinv = inv[(b << 10) + m];

    const unsigned short* qhi = hqHI + ((size_t)(b << 10)) * HID;
    const unsigned short* qlo = hqLO + ((size_t)(b << 10)) * HID;
    const unsigned short* vb0 = hkDB + (size_t)(b * HID + c) * KTOT;
    const unsigned short* vb1 = hkDB + (size_t)(b * HID + 16 + c) * KTOT;
    float* attb = att + (size_t)b * KTOT * NN;

    // per-wave P-transpose tile: PT[m-local][k-local(32)], stride 40 (bank spread)
    __shared__ __align__(16) unsigned short PT[4][16][40];
    unsigned short (*pt)[40] = PT[wave];

    f32x4 acc0 = {0.f,0.f,0.f,0.f}, acc1 = {0.f,0.f,0.f,0.f};

    for (int ks = 0; ks < KCHUNK / 32; ks++) {     // 16 iters, 32 k each
        int k0 = kc * KCHUNK + ks * 32;
#pragma unroll
        for (int half = 0; half < 2; half++) {
            int kb = k0 + half * 16;
            int nb = kb & 1023;
            size_t ao = (size_t)(nb + c) * HID + 8 * g;
            bf16x8 ah = *(const bf16x8*)(qhi + ao);
            bf16x8 al = *(const bf16x8*)(qlo + ao);
            f32x4 sv = __builtin_amdgcn_mfma_f32_16x16x32_bf16(ah, bql, (f32x4){0.f,0.f,0.f,0.f}, 0, 0, 0);
            sv = __builtin_amdgcn_mfma_f32_16x16x32_bf16(al, bqh, sv, 0, 0, 0);
            sv = __builtin_amdgcn_mfma_f32_16x16x32_bf16(ah, bqh, sv, 0, 0, 0);
            int krow = kb + 4 * g;                 // global row k
            int nrow = nb + 4 * g;                 // query n
            float e[4];
#pragma unroll
            for (int r = 0; r < 4; r++) {
                float x = (nrow + r == m) ? 0.f : sv[r];
                e[r] = __expf(x) * vinv;
                attb[(size_t)(krow + r) * NN + m] = e[r];   // coalesced 64B chunks
            }
            unsigned int p01 = (unsigned int)f2b(e[0]) | ((unsigned int)f2b(e[1]) << 16);
            unsigned int p23 = (unsigned int)f2b(e[2]) | ((unsigned int)f2b(e[3]) << 16);
            *(unsigned int*)&pt[c][half * 16 + 4 * g]     = p01;
            *(unsigned int*)&pt[c][half * 16 + 4 * g + 2] = p23;
        }
        // GEMM2: hv[m,d] += sum_k att[k,m] * V[k,d]   (V = H_kv rows)
        bf16x8 pa = *(const bf16x8*)&pt[c][8 * g];        // A2[m=c][k=8g+j]
        bf16x8 v0 = *(const bf16x8*)(vb0 + k0 + 8 * g);   // B2[k][d=c]
        bf16x8 v1 = *(const bf16x8*)(vb1 + k0 + 8 * g);   // B2[k][d=16+c]
        acc0 = __builtin_amdgcn_mfma_f32_16x16x32_bf16(pa, v0, acc0, 0, 0, 0);
        acc1 = __builtin_amdgcn_mfma_f32_16x16x32_bf16(pa, v1, acc1, 0, 0, 0);
    }
    // hvp[b][kc][m][d]; D2 row = m-local (4g+r), col = d (c / 16+c)
    float* o = hvp + ((((size_t)(b * NKC + kc)) << 10) + mt * 64 + wave * 16) * HID;
#pragma unroll
    for (int r = 0; r < 4; r++) {
        o[(size_t)(4 * g + r) * HID + c]      = acc0[r];
        o[(size_t)(4 * g + r) * HID + 16 + c] = acc1[r];
    }
}

// ---- reduce hv partials over kc: hv2[b][m][d] ----
__global__ __launch_bounds__(256) void k_red(const float* __restrict__ hvp,
                                             float* __restrict__ hv2) {
    int gid = blockIdx.x * 256 + threadIdx.x;      // 131072 (b, m*32+d)
    int b = gid >> 15, md = gid & 32767;
    float s = 0.f;
#pragma unroll
    for (int kc = 0; kc < NKC; kc++)
        s += hvp[(((size_t)(b * NKC + kc)) << 15) + md];
    hv2[gid] = s;
}

// ---- out0[b,c,m] = h[b,c,m] + sum_d w_o[c,d] * hv2[b][m][d] ----
__global__ __launch_bounds__(256) void k_out(const float* __restrict__ h,
                                             const float* __restrict__ wo,
                                             const float* __restrict__ hv2,
                                             float* __restrict__ out0) {
    int bx = blockIdx.x;                           // 128: b(4) x mt(32)
    int b = bx >> 5, mt = bx & 31;
    int m0 = mt * 32;
    int tid = threadIdx.x;
    __shared__ float hvL[32][33];
    for (int i = tid; i < 1024; i += 256) {
        int mm = i >> 5, d = i & 31;
        hvL[mm][d] = hv2[((size_t)(b << 10) + m0 + mm) * HID + d];  // coalesced
    }
    __syncthreads();
    for (int i = tid; i < CC * 32; i += 256) {
        int c = i >> 5, mm = i & 31;
        float v = h[(size_t)(b * CC + c) * NN + m0 + mm];
#pragma unroll
        for (int d = 0; d < HID; d++) v += wo[c * HID + d] * hvL[mm][d];
        out0[(size_t)(b * CC + c) * NN + m0 + mm] = v;
    }
}

extern "C" void kernel_launch(void* const* d_in, const int* in_sizes, int n_in,
                              void* d_out, int out_size, void* d_ws, size_t ws_size,
                              hipStream_t stream) {
    const float* H   = (const float*)d_in[0];
    const float* h   = (const float*)d_in[1];
    const float* wq  = (const float*)d_in[2];
    const float* wkv = (const float*)d_in[3];
    const float* wo  = (const float*)d_in[4];

    float* out0 = (float*)d_out;                       // [4,64,32,32]
    float* att  = out0 + (size_t)BB * CC * NN;         // [4,8192,1024]

    unsigned short* hqHI  = (unsigned short*)d_ws;     // 131072
    unsigned short* hqLO  = hqHI  + 131072;            // 131072
    unsigned short* hkTHI = hqLO  + 131072;            // 1048576
    unsigned short* hkTLO = hkTHI + 1048576;           // 1048576
    unsigned short* hkDB  = hkTLO + 1048576;           // 1048576
    float* psum = (float*)(hkDB + 1048576);            // 65536
    float* inv  = psum + 65536;                        // 4096
    float* hvp  = inv  + 4096;                         // 2097152
    float* hv2  = hvp  + 2097152;                      // 131072  (~16 MB total)

    k_hq  <<<16,   256, 0, stream>>>(h, wq, hqHI, hqLO);
    k_hkv <<<128,  256, 0, stream>>>(H, wkv, hkTHI, hkTLO, hkDB);
    k_psum<<<1024, 256, 0, stream>>>(hqHI, hqLO, hkTHI, hkTLO, psum);
    k_inv <<<16,   256, 0, stream>>>(psum, inv);
    k_att2<<<1024, 256, 0, stream>>>(hqHI, hqLO, hkTHI, hkTLO, hkDB, inv, att, hvp);
    k_red <<<512,  256, 0, stream>>>(hvp, hv2);
    k_out <<<128,  256, 0, stream>>>(h, wo, hv2, out0);
}

// Round 6
// 120.068 us; speedup vs baseline: 3.8292x; 1.0199x over previous
//
#include <hip/hip_runtime.h>

typedef short bf16x8 __attribute__((ext_vector_type(8)));
typedef float f32x4  __attribute__((ext_vector_type(4)));
typedef unsigned short ushort_t;

#define HID 32
#define CC  64
#define TT  8
#define NN  1024
#define BB  4
#define KTOT 8192
#define NKC 16                 // k-chunks; KCHUNK=512 divides NN -> single t per chunk
#define KCHUNK (KTOT/NKC)      // 512

// f32 -> bf16 (RNE)
__device__ __forceinline__ ushort_t f2b(float x) {
    unsigned int u = __float_as_uint(x);
    return (ushort_t)((u + 0x7fffu + ((u >> 16) & 1u)) >> 16);
}
__device__ __forceinline__ float b2f(ushort_t u) {
    return __uint_as_float((unsigned int)u << 16);
}

// ---------------- K1a: h_q[b,n,d] hi/lo bf16 split, layout [b*N+n][32] ----------------
__global__ __launch_bounds__(256) void k_hq(const float* __restrict__ h,
                                            const float* __restrict__ wq,
                                            ushort_t* __restrict__ hqHI,
                                            ushort_t* __restrict__ hqLO) {
    int gid = blockIdx.x * 256 + threadIdx.x;      // 0..4095  (b,n)
    int b = gid >> 10;
    float acc[HID];
#pragma unroll
    for (int d = 0; d < HID; d++) acc[d] = 0.f;
    const float* hb = h + (size_t)(b * CC) * NN + (gid & 1023);
    for (int c = 0; c < CC; c++) {
        float v = hb[c * NN];                      // coalesced
#pragma unroll
        for (int d = 0; d < HID; d++) acc[d] += wq[d * CC + c] * v;  // uniform -> s_load
    }
    bf16x8* ohi = (bf16x8*)(hqHI + (size_t)gid * HID);
    bf16x8* olo = (bf16x8*)(hqLO + (size_t)gid * HID);
#pragma unroll
    for (int v8 = 0; v8 < 4; v8++) {
        bf16x8 thi, tlo;
#pragma unroll
        for (int j = 0; j < 8; j++) {
            float x = acc[v8 * 8 + j];
            ushort_t hi = f2b(x);
            thi[j] = (short)hi;
            tlo[j] = (short)f2b(x - b2f(hi));
        }
        ohi[v8] = thi; olo[v8] = tlo;
    }
}

// --- K1b: hkT hi/lo in four 16-wide planes [b*KTOT+tn][16] + hkDB (d-major bf16) ---
// grid 256: dg(2) x b(4) x tn(8192); dg selects d-half
__global__ __launch_bounds__(256) void k_hkv(const float* __restrict__ H,
                                             const float* __restrict__ wkv,
                                             ushort_t* __restrict__ hkTH0,
                                             ushort_t* __restrict__ hkTH1,
                                             ushort_t* __restrict__ hkTL0,
                                             ushort_t* __restrict__ hkTL1,
                                             ushort_t* __restrict__ hkDB) {
    int gid = blockIdx.x * 256 + threadIdx.x;      // 0..65535
    int dg = gid >> 15;                            // block-uniform
    int rest = gid & 32767;
    int b = rest >> 13, tn = rest & 8191;
    int d0 = dg << 4;
    float acc[16];
#pragma unroll
    for (int d = 0; d < 16; d++) acc[d] = 0.f;
    const float* Hb = H + (size_t)(b * CC) * KTOT + tn;
    const float* wb = wkv + d0 * CC;
    for (int c = 0; c < CC; c++) {
        float v = Hb[(size_t)c * KTOT];            // coalesced
#pragma unroll
        for (int d = 0; d < 16; d++) acc[d] += wb[d * CC + c] * v;   // uniform -> s_load
    }
    ushort_t thi[16], tlo[16];
#pragma unroll
    for (int d = 0; d < 16; d++) {
        ushort_t hi = f2b(acc[d]);
        thi[d] = hi;
        tlo[d] = f2b(acc[d] - b2f(hi));
    }
    size_t po = ((size_t)b * KTOT + tn) * 16;
    bf16x8* ohi = (bf16x8*)((dg ? hkTH1 : hkTH0) + po);
    bf16x8* olo = (bf16x8*)((dg ? hkTL1 : hkTL0) + po);
#pragma unroll
    for (int v8 = 0; v8 < 2; v8++) {
        bf16x8 a, l;
#pragma unroll
        for (int j = 0; j < 8; j++) { a[j] = (short)thi[v8*8+j]; l[j] = (short)tlo[v8*8+j]; }
        ohi[v8] = a; olo[v8] = l;
    }
#pragma unroll
    for (int d = 0; d < 16; d++)
        hkDB[((size_t)(b * HID) + d0 + d) * KTOT + tn] = thi[d];   // coalesced per d
}

// ---- Pass A: psum[b][kc][m] = sum over chunk rows k=(t,n) of exp(score) ----
// score[k=(t,n)][m] = dot_d hq[n,d] * hkT[t*NN+m, d];  diag (n==m) -> 0
__global__ __launch_bounds__(256) void k_psum(const ushort_t* __restrict__ hqHI,
                                              const ushort_t* __restrict__ hqLO,
                                              const ushort_t* __restrict__ hkTH0,
                                              const ushort_t* __restrict__ hkTH1,
                                              const ushort_t* __restrict__ hkTL0,
                                              const ushort_t* __restrict__ hkTL1,
                                              float* __restrict__ psum) {
    int bx = blockIdx.x;                           // 1024: b(4) x mt(16) x kc(16)
    int b = bx >> 8, mt = (bx >> 4) & 15, kc = bx & 15;
    int wave = threadIdx.x >> 6, lane = threadIdx.x & 63;
    int g = lane >> 4, c = lane & 15;
    int m = mt * 64 + wave * 16 + c;
    int t = kc >> 1;
    int nb0 = (kc & 1) << 9;                       // chunk covers n in [nb0, nb0+512)

    // B frag: key column hkT[t,m], hi/lo, from plane g>>1 at offset (g&1)*8
    size_t bqo = ((size_t)b * KTOT + t * NN + m) * 16 + (g & 1) * 8;
    bf16x8 bqh = *(const bf16x8*)(((g >> 1) ? hkTH1 : hkTH0) + bqo);
    bf16x8 bql = *(const bf16x8*)(((g >> 1) ? hkTL1 : hkTL0) + bqo);

    const ushort_t* qhi = hqHI + ((size_t)(b << 10)) * HID;
    const ushort_t* qlo = hqLO + ((size_t)(b << 10)) * HID;

    float csum0 = 0.f, csum1 = 0.f;
    for (int s16 = 0; s16 < KCHUNK / 16; s16 += 2) {  // 16 iters, 2 tiles each
        int nbA = nb0 + s16 * 16;
        int nbB = nbA + 16;
        size_t aoA = (size_t)(nbA + c) * HID + 8 * g;
        size_t aoB = (size_t)(nbB + c) * HID + 8 * g;
        bf16x8 ahA = *(const bf16x8*)(qhi + aoA);
        bf16x8 alA = *(const bf16x8*)(qlo + aoA);
        bf16x8 ahB = *(const bf16x8*)(qhi + aoB);
        bf16x8 alB = *(const bf16x8*)(qlo + aoB);
        f32x4 svA = __builtin_amdgcn_mfma_f32_16x16x32_bf16(ahA, bql, (f32x4){0.f,0.f,0.f,0.f}, 0, 0, 0);
        f32x4 svB = __builtin_amdgcn_mfma_f32_16x16x32_bf16(ahB, bql, (f32x4){0.f,0.f,0.f,0.f}, 0, 0, 0);
        svA = __builtin_amdgcn_mfma_f32_16x16x32_bf16(alA, bqh, svA, 0, 0, 0);
        svB = __builtin_amdgcn_mfma_f32_16x16x32_bf16(alB, bqh, svB, 0, 0, 0);
        svA = __builtin_amdgcn_mfma_f32_16x16x32_bf16(ahA, bqh, svA, 0, 0, 0);
        svB = __builtin_amdgcn_mfma_f32_16x16x32_bf16(ahB, bqh, svB, 0, 0, 0);
        int nrowA = nbA + 4 * g;                   // D row = query n
        int nrowB = nbB + 4 * g;
#pragma unroll
        for (int r = 0; r < 4; r++) {
            float xA = (nrowA + r == m) ? 0.f : svA[r];
            float xB = (nrowB + r == m) ? 0.f : svB[r];
            csum0 += __expf(xA);
            csum1 += __expf(xB);
        }
    }
    float csum = csum0 + csum1;
    csum += __shfl_xor(csum, 16);
    csum += __shfl_xor(csum, 32);
    if (lane < 16)
        psum[(((size_t)(b * NKC + kc)) << 10) + mt * 64 + wave * 16 + lane] = csum;
}

// ---- Pass B: inv + att (coalesced) + fused hv partials ----
__global__ __launch_bounds__(256) void k_att2(const ushort_t* __restrict__ hqHI,
                                              const ushort_t* __restrict__ hqLO,
                                              const ushort_t* __restrict__ hkTH0,
                                              const ushort_t* __restrict__ hkTH1,
                                              const ushort_t* __restrict__ hkTL0,
                                              const ushort_t* __restrict__ hkTL1,
                                              const ushort_t* __restrict__ hkDB,
                                              const float* __restrict__ psum,
                                              float* __restrict__ att,
                                              float* __restrict__ hvp) {
    int bx = blockIdx.x;                           // 1024: b(4) x mt(16) x kc(16)
    int b = bx >> 8, mt = (bx >> 4) & 15, kc = bx & 15;
    int wave = threadIdx.x >> 6, lane = threadIdx.x & 63;
    int g = lane >> 4, c = lane & 15;
    int m = mt * 64 + wave * 16 + c;
    int t = kc >> 1;
    int nb0 = (kc & 1) << 9;

    // denominator: sum the 16 chunk partials for this (b,m)
    float gsum = 0.f;
#pragma unroll
    for (int j = 0; j < NKC; j++)
        gsum += psum[(((size_t)(b * NKC + j)) << 10) + m];   // coalesced
    float vinv = 1.0f / gsum;

    size_t bqo = ((size_t)b * KTOT + t * NN + m) * 16 + (g & 1) * 8;
    bf16x8 bqh = *(const bf16x8*)(((g >> 1) ? hkTH1 : hkTH0) + bqo);
    bf16x8 bql = *(const bf16x8*)(((g >> 1) ? hkTL1 : hkTL0) + bqo);

    const ushort_t* qhi = hqHI + ((size_t)(b << 10)) * HID;
    const ushort_t* qlo = hqLO + ((size_t)(b << 10)) * HID;
    const ushort_t* vb0 = hkDB + (size_t)(b * HID + c) * KTOT;
    const ushort_t* vb1 = hkDB + (size_t)(b * HID + 16 + c) * KTOT;
    float* attb = att + (size_t)b * KTOT * NN;

    // per-wave P-transpose tile: PT[m-local][k-local(32)], stride 40 (bank spread)
    __shared__ __align__(16) ushort_t PT[4][16][40];
    ushort_t (*pt)[40] = PT[wave];

    f32x4 acc0 = {0.f,0.f,0.f,0.f}, acc1 = {0.f,0.f,0.f,0.f};

    for (int ks = 0; ks < KCHUNK / 32; ks++) {     // 16 iters, 32 k each
        int k0 = kc * KCHUNK + ks * 32;
#pragma unroll
        for (int half = 0; half < 2; half++) {
            int kb = k0 + half * 16;
            int nb = kb & 1023;
            size_t ao = (size_t)(nb + c) * HID + 8 * g;
            bf16x8 ah = *(const bf16x8*)(qhi + ao);
            bf16x8 al = *(const bf16x8*)(qlo + ao);
            f32x4 sv = __builtin_amdgcn_mfma_f32_16x16x32_bf16(ah, bql, (f32x4){0.f,0.f,0.f,0.f}, 0, 0, 0);
            sv = __builtin_amdgcn_mfma_f32_16x16x32_bf16(al, bqh, sv, 0, 0, 0);
            sv = __builtin_amdgcn_mfma_f32_16x16x32_bf16(ah, bqh, sv, 0, 0, 0);
            int krow = kb + 4 * g;                 // global row k
            int nrow = nb + 4 * g;                 // query n
            float e[4];
#pragma unroll
            for (int r = 0; r < 4; r++) {
                float x = (nrow + r == m) ? 0.f : sv[r];
                e[r] = __expf(x) * vinv;
                attb[(size_t)(krow + r) * NN + m] = e[r];   // 4 rows x 64B
            }
            unsigned int p01 = (unsigned int)f2b(e[0]) | ((unsigned int)f2b(e[1]) << 16);
            unsigned int p23 = (unsigned int)f2b(e[2]) | ((unsigned int)f2b(e[3]) << 16);
            *(unsigned int*)&pt[c][half * 16 + 4 * g]     = p01;
            *(unsigned int*)&pt[c][half * 16 + 4 * g + 2] = p23;
        }
        // GEMM2: hv[m,d] += sum_k att[k,m] * V[k,d]   (V = H_kv rows)
        bf16x8 pa = *(const bf16x8*)&pt[c][8 * g];        // A2[m=c][k=8g+j]
        bf16x8 v0 = *(const bf16x8*)(vb0 + k0 + 8 * g);   // B2[k][d=c]
        bf16x8 v1 = *(const bf16x8*)(vb1 + k0 + 8 * g);   // B2[k][d=16+c]
        acc0 = __builtin_amdgcn_mfma_f32_16x16x32_bf16(pa, v0, acc0, 0, 0, 0);
        acc1 = __builtin_amdgcn_mfma_f32_16x16x32_bf16(pa, v1, acc1, 0, 0, 0);
    }
    // hvp[b][kc][m][d]; D2 row = m-local (4g+r), col = d (c / 16+c)
    float* o = hvp + ((((size_t)(b * NKC + kc)) << 10) + mt * 64 + wave * 16) * HID;
#pragma unroll
    for (int r = 0; r < 4; r++) {
        o[(size_t)(4 * g + r) * HID + c]      = acc0[r];
        o[(size_t)(4 * g + r) * HID + 16 + c] = acc1[r];
    }
}

// ---- out0[b,c,m] = h[b,c,m] + sum_d w_o[c,d] * (sum_kc hvp[b][kc][m][d]) ----
__global__ __launch_bounds__(256) void k_out(const float* __restrict__ h,
                                             const float* __restrict__ wo,
                                             const float* __restrict__ hvp,
                                             float* __restrict__ out0) {
    int bx = blockIdx.x;                           // 128: b(4) x mt(32)
    int b = bx >> 5, mt = bx & 31;
    int m0 = mt * 32;
    int tid = threadIdx.x;
    __shared__ float hvL[32][33];
    for (int i = tid; i < 1024; i += 256) {
        int mm = i >> 5, d = i & 31;
        float s = 0.f;
#pragma unroll
        for (int kc = 0; kc < NKC; kc++)
            s += hvp[(((size_t)(b * NKC + kc)) << 15) + (size_t)(m0 + mm) * HID + d]; // coalesced
        hvL[mm][d] = s;
    }
    __syncthreads();
    for (int i = tid; i < CC * 32; i += 256) {
        int c = i >> 5, mm = i & 31;
        float v = h[(size_t)(b * CC + c) * NN + m0 + mm];
#pragma unroll
        for (int d = 0; d < HID; d++) v += wo[c * HID + d] * hvL[mm][d];
        out0[(size_t)(b * CC + c) * NN + m0 + mm] = v;
    }
}

extern "C" void kernel_launch(void* const* d_in, const int* in_sizes, int n_in,
                              void* d_out, int out_size, void* d_ws, size_t ws_size,
                              hipStream_t stream) {
    const float* H   = (const float*)d_in[0];
    const float* h   = (const float*)d_in[1];
    const float* wq  = (const float*)d_in[2];
    const float* wkv = (const float*)d_in[3];
    const float* wo  = (const float*)d_in[4];

    float* out0 = (float*)d_out;                       // [4,64,32,32]
    float* att  = out0 + (size_t)BB * CC * NN;         // [4,8192,1024]

    ushort_t* hqHI  = (ushort_t*)d_ws;                 // 131072
    ushort_t* hqLO  = hqHI  + 131072;                  // 131072
    ushort_t* hkTH0 = hqLO  + 131072;                  // 524288
    ushort_t* hkTH1 = hkTH0 + 524288;                  // 524288
    ushort_t* hkTL0 = hkTH1 + 524288;                  // 524288
    ushort_t* hkTL1 = hkTL0 + 524288;                  // 524288
    ushort_t* hkDB  = hkTL1 + 524288;                  // 1048576
    float* psum = (float*)(hkDB + 1048576);            // 65536
    float* hvp  = psum + 65536;                        // 2097152  (~15.5 MB total)

    k_hq  <<<16,   256, 0, stream>>>(h, wq, hqHI, hqLO);
    k_hkv <<<256,  256, 0, stream>>>(H, wkv, hkTH0, hkTH1, hkTL0, hkTL1, hkDB);
    k_psum<<<1024, 256, 0, stream>>>(hqHI, hqLO, hkTH0, hkTH1, hkTL0, hkTL1, psum);
    k_att2<<<1024, 256, 0, stream>>>(hqHI, hqLO, hkTH0, hkTH1, hkTL0, hkTL1, hkDB, psum, att, hvp);
    k_out <<<128,  256, 0, stream>>>(h, wo, hvp, out0);
}

// Round 7
// 105.338 us; speedup vs baseline: 4.3647x; 1.1398x over previous
//
#include <hip/hip_runtime.h>

typedef short bf16x8 __attribute__((ext_vector_type(8)));
typedef float f32x4  __attribute__((ext_vector_type(4)));
typedef unsigned short ushort_t;

#define HID 32
#define CC  64
#define TT  8
#define NN  1024
#define BB  4
#define KTOT 8192
#define NKC 16                 // k-chunks; KCHUNK=512 divides NN -> single t per chunk
#define KCHUNK (KTOT/NKC)      // 512

// f32 -> bf16 (RNE)
__device__ __forceinline__ ushort_t f2b(float x) {
    unsigned int u = __float_as_uint(x);
    return (ushort_t)((u + 0x7fffu + ((u >> 16) & 1u)) >> 16);
}
__device__ __forceinline__ float b2f(ushort_t u) {
    return __uint_as_float((unsigned int)u << 16);
}

// --- K1 fused: blocks 0..255 -> hkT planes + hkDB;  blocks 256..271 -> hq hi/lo ---
__global__ __launch_bounds__(256) void k_pre(const float* __restrict__ H,
                                             const float* __restrict__ h,
                                             const float* __restrict__ wq,
                                             const float* __restrict__ wkv,
                                             ushort_t* __restrict__ hqHI,
                                             ushort_t* __restrict__ hqLO,
                                             ushort_t* __restrict__ hkTH0,
                                             ushort_t* __restrict__ hkTH1,
                                             ushort_t* __restrict__ hkTL0,
                                             ushort_t* __restrict__ hkTL1,
                                             ushort_t* __restrict__ hkDB) {
    int bx = blockIdx.x;
    if (bx < 256) {
        // H_kv: hi/lo k-major planes (16-wide) + d-major bf16
        int gid = bx * 256 + threadIdx.x;          // 0..65535
        int dg = gid >> 15;                        // block-uniform d-half
        int rest = gid & 32767;
        int b = rest >> 13, tn = rest & 8191;
        int d0 = dg << 4;
        float acc[16];
#pragma unroll
        for (int d = 0; d < 16; d++) acc[d] = 0.f;
        const float* Hb = H + (size_t)(b * CC) * KTOT + tn;
        const float* wb = wkv + d0 * CC;
        for (int c = 0; c < CC; c++) {
            float v = Hb[(size_t)c * KTOT];        // coalesced
#pragma unroll
            for (int d = 0; d < 16; d++) acc[d] += wb[d * CC + c] * v;  // uniform -> s_load
        }
        ushort_t thi[16], tlo[16];
#pragma unroll
        for (int d = 0; d < 16; d++) {
            ushort_t hi = f2b(acc[d]);
            thi[d] = hi;
            tlo[d] = f2b(acc[d] - b2f(hi));
        }
        size_t po = ((size_t)b * KTOT + tn) * 16;
        bf16x8* ohi = (bf16x8*)((dg ? hkTH1 : hkTH0) + po);
        bf16x8* olo = (bf16x8*)((dg ? hkTL1 : hkTL0) + po);
#pragma unroll
        for (int v8 = 0; v8 < 2; v8++) {
            bf16x8 a, l;
#pragma unroll
            for (int j = 0; j < 8; j++) { a[j] = (short)thi[v8*8+j]; l[j] = (short)tlo[v8*8+j]; }
            ohi[v8] = a; olo[v8] = l;
        }
#pragma unroll
        for (int d = 0; d < 16; d++)
            hkDB[((size_t)(b * HID) + d0 + d) * KTOT + tn] = thi[d];   // coalesced per d
    } else {
        // h_q hi/lo, layout [b*N+n][32]
        int gid = (bx - 256) * 256 + threadIdx.x;  // 0..4095
        int b = gid >> 10;
        float acc[HID];
#pragma unroll
        for (int d = 0; d < HID; d++) acc[d] = 0.f;
        const float* hb = h + (size_t)(b * CC) * NN + (gid & 1023);
        for (int c = 0; c < CC; c++) {
            float v = hb[c * NN];                  // coalesced
#pragma unroll
            for (int d = 0; d < HID; d++) acc[d] += wq[d * CC + c] * v;
        }
        bf16x8* ohi = (bf16x8*)(hqHI + (size_t)gid * HID);
        bf16x8* olo = (bf16x8*)(hqLO + (size_t)gid * HID);
#pragma unroll
        for (int v8 = 0; v8 < 4; v8++) {
            bf16x8 thi, tlo;
#pragma unroll
            for (int j = 0; j < 8; j++) {
                float x = acc[v8 * 8 + j];
                ushort_t hi = f2b(x);
                thi[j] = (short)hi;
                tlo[j] = (short)f2b(x - b2f(hi));
            }
            ohi[v8] = thi; olo[v8] = tlo;
        }
    }
}

// ---- Pass A: psum[b][kc][m] = sum over chunk rows k=(t,n) of exp(score) ----
// D[n][m] orientation (A=query rows, B=key col). 512 blocks x 512 thr, m-range 128.
__global__ __launch_bounds__(512) void k_psum(const ushort_t* __restrict__ hqHI,
                                              const ushort_t* __restrict__ hqLO,
                                              const ushort_t* __restrict__ hkTH0,
                                              const ushort_t* __restrict__ hkTH1,
                                              const ushort_t* __restrict__ hkTL0,
                                              const ushort_t* __restrict__ hkTL1,
                                              float* __restrict__ psum) {
    int bx = blockIdx.x;                           // 512: b(4) x mt(8) x kc(16)
    int b = bx >> 7, mt = (bx >> 4) & 7, kc = bx & 15;
    int wave = threadIdx.x >> 6, lane = threadIdx.x & 63;
    int g = lane >> 4, c = lane & 15;
    int m = mt * 128 + wave * 16 + c;
    int t = kc >> 1;
    int nb0 = (kc & 1) << 9;                       // chunk covers n in [nb0, nb0+512)

    // B frag: key column hkT[t,m], hi/lo, plane g>>1, offset (g&1)*8
    size_t bqo = ((size_t)b * KTOT + t * NN + m) * 16 + (g & 1) * 8;
    bf16x8 bqh = *(const bf16x8*)(((g >> 1) ? hkTH1 : hkTH0) + bqo);
    bf16x8 bql = *(const bf16x8*)(((g >> 1) ? hkTL1 : hkTL0) + bqo);

    const ushort_t* qhi = hqHI + ((size_t)(b << 10)) * HID;
    const ushort_t* qlo = hqLO + ((size_t)(b << 10)) * HID;

    float csum0 = 0.f, csum1 = 0.f;
    for (int s16 = 0; s16 < KCHUNK / 16; s16 += 2) {  // 16 iters, 2 tiles each
        int nbA = nb0 + s16 * 16;
        int nbB = nbA + 16;
        size_t aoA = (size_t)(nbA + c) * HID + 8 * g;
        size_t aoB = (size_t)(nbB + c) * HID + 8 * g;
        bf16x8 ahA = *(const bf16x8*)(qhi + aoA);
        bf16x8 alA = *(const bf16x8*)(qlo + aoA);
        bf16x8 ahB = *(const bf16x8*)(qhi + aoB);
        bf16x8 alB = *(const bf16x8*)(qlo + aoB);
        f32x4 svA = __builtin_amdgcn_mfma_f32_16x16x32_bf16(ahA, bql, (f32x4){0.f,0.f,0.f,0.f}, 0, 0, 0);
        f32x4 svB = __builtin_amdgcn_mfma_f32_16x16x32_bf16(ahB, bql, (f32x4){0.f,0.f,0.f,0.f}, 0, 0, 0);
        svA = __builtin_amdgcn_mfma_f32_16x16x32_bf16(alA, bqh, svA, 0, 0, 0);
        svB = __builtin_amdgcn_mfma_f32_16x16x32_bf16(alB, bqh, svB, 0, 0, 0);
        svA = __builtin_amdgcn_mfma_f32_16x16x32_bf16(ahA, bqh, svA, 0, 0, 0);
        svB = __builtin_amdgcn_mfma_f32_16x16x32_bf16(ahB, bqh, svB, 0, 0, 0);
        int nrowA = nbA + 4 * g;                   // D row = query n
        int nrowB = nbB + 4 * g;
#pragma unroll
        for (int r = 0; r < 4; r++) {
            float xA = (nrowA + r == m) ? 0.f : svA[r];
            float xB = (nrowB + r == m) ? 0.f : svB[r];
            csum0 += __expf(xA);
            csum1 += __expf(xB);
        }
    }
    float csum = csum0 + csum1;
    csum += __shfl_xor(csum, 16);
    csum += __shfl_xor(csum, 32);
    if (lane < 16)
        psum[(((size_t)(b * NKC + kc)) << 10) + mt * 128 + wave * 16 + lane] = csum;
}

// ---- Pass B: S^T orientation (A=key m-tile, B=query n-tile) -> dwordx4 att stores ----
__global__ __launch_bounds__(512) void k_att2(const ushort_t* __restrict__ hqHI,
                                              const ushort_t* __restrict__ hqLO,
                                              const ushort_t* __restrict__ hkTH0,
                                              const ushort_t* __restrict__ hkTH1,
                                              const ushort_t* __restrict__ hkTL0,
                                              const ushort_t* __restrict__ hkTL1,
                                              const ushort_t* __restrict__ hkDB,
                                              const float* __restrict__ psum,
                                              float* __restrict__ att,
                                              float* __restrict__ hvp) {
    int bx = blockIdx.x;                           // 512: b(4) x mt(8) x kc(16)
    int b = bx >> 7, mt = (bx >> 4) & 7, kc = bx & 15;
    int wave = threadIdx.x >> 6, lane = threadIdx.x & 63;
    int g = lane >> 4, c = lane & 15;
    int mb = mt * 128 + wave * 16;                 // wave's 16-wide m-tile
    int t = kc >> 1;
    int nb0 = (kc & 1) << 9;

    // denominators for this lane's 4 m's (m = mb + 4g + r)
    f32x4 gs = {0.f, 0.f, 0.f, 0.f};
#pragma unroll
    for (int j = 0; j < NKC; j++)
        gs += *(const f32x4*)(psum + (((size_t)(b * NKC + j)) << 10) + mb + 4 * g);
    f32x4 vinv;
#pragma unroll
    for (int r = 0; r < 4; r++) vinv[r] = 1.0f / gs[r];

    // A frag (loop-invariant): key[m = mb + c][d = 8g+j], hi/lo
    size_t ako = ((size_t)b * KTOT + t * NN + (mb + c)) * 16 + (g & 1) * 8;
    bf16x8 akh = *(const bf16x8*)(((g >> 1) ? hkTH1 : hkTH0) + ako);
    bf16x8 akl = *(const bf16x8*)(((g >> 1) ? hkTL1 : hkTL0) + ako);

    const ushort_t* qhi = hqHI + ((size_t)(b << 10)) * HID;
    const ushort_t* qlo = hqLO + ((size_t)(b << 10)) * HID;
    const ushort_t* vb0 = hkDB + (size_t)(b * HID + c) * KTOT;
    const ushort_t* vb1 = hkDB + (size_t)(b * HID + 16 + c) * KTOT;
    float* attb = att + (size_t)b * KTOT * NN;

    // per-wave P-transpose tile: PT[m-local 16][k-local 32 pad->40]
    __shared__ __align__(16) ushort_t PT[8][16][40];
    ushort_t (*pt)[40] = PT[wave];

    f32x4 acc0 = {0.f,0.f,0.f,0.f}, acc1 = {0.f,0.f,0.f,0.f};

    for (int ks = 0; ks < KCHUNK / 32; ks++) {     // 16 iters, 32 k each
        int k0 = kc * KCHUNK + ks * 32;
#pragma unroll
        for (int half = 0; half < 2; half++) {
            int nb = nb0 + ks * 32 + half * 16;    // n-tile base
            size_t qo = (size_t)(nb + c) * HID + 8 * g;
            bf16x8 qh = *(const bf16x8*)(qhi + qo);
            bf16x8 ql = *(const bf16x8*)(qlo + qo);
            // S^T[m][n] = sum_d key[m,d]*q[n,d]  (hi*lo + lo*hi + hi*hi)
            f32x4 sv = __builtin_amdgcn_mfma_f32_16x16x32_bf16(akh, ql, (f32x4){0.f,0.f,0.f,0.f}, 0, 0, 0);
            sv = __builtin_amdgcn_mfma_f32_16x16x32_bf16(akl, qh, sv, 0, 0, 0);
            sv = __builtin_amdgcn_mfma_f32_16x16x32_bf16(akh, qh, sv, 0, 0, 0);
            int n = nb + c;                        // this lane's att row (k = t*NN + n)
            float4 ev;
            float e0, e1, e2, e3;
            {
                float x0 = (n == mb + 4 * g + 0) ? 0.f : sv[0];
                float x1 = (n == mb + 4 * g + 1) ? 0.f : sv[1];
                float x2 = (n == mb + 4 * g + 2) ? 0.f : sv[2];
                float x3 = (n == mb + 4 * g + 3) ? 0.f : sv[3];
                e0 = __expf(x0) * vinv[0];
                e1 = __expf(x1) * vinv[1];
                e2 = __expf(x2) * vinv[2];
                e3 = __expf(x3) * vinv[3];
            }
            ev.x = e0; ev.y = e1; ev.z = e2; ev.w = e3;
            *(float4*)(attb + (size_t)(t * NN + n) * NN + mb + 4 * g) = ev;  // 16B/lane
            // PT[m-local][k-local]: m-local = 4g+r, k-local = half*16 + c
            int kl = half * 16 + c;
            pt[4 * g + 0][kl] = f2b(e0);
            pt[4 * g + 1][kl] = f2b(e1);
            pt[4 * g + 2][kl] = f2b(e2);
            pt[4 * g + 3][kl] = f2b(e3);
        }
        // GEMM2: hv[m,d] += sum_k P[m,k] * V[k,d]
        bf16x8 pa = *(const bf16x8*)&pt[c][8 * g];        // A2[m=c][k=8g+j]
        bf16x8 v0 = *(const bf16x8*)(vb0 + k0 + 8 * g);   // B2[k][d=c]
        bf16x8 v1 = *(const bf16x8*)(vb1 + k0 + 8 * g);   // B2[k][d=16+c]
        acc0 = __builtin_amdgcn_mfma_f32_16x16x32_bf16(pa, v0, acc0, 0, 0, 0);
        acc1 = __builtin_amdgcn_mfma_f32_16x16x32_bf16(pa, v1, acc1, 0, 0, 0);
    }
    // hvp[b][kc][m][d]; D2 row = m-local (4g+r), col = d (c / 16+c)
    float* o = hvp + ((((size_t)(b * NKC + kc)) << 10) + mb) * HID;
#pragma unroll
    for (int r = 0; r < 4; r++) {
        o[(size_t)(4 * g + r) * HID + c]      = acc0[r];
        o[(size_t)(4 * g + r) * HID + 16 + c] = acc1[r];
    }
}

// ---- out0[b,c,m] = h[b,c,m] + sum_d w_o[c,d] * (sum_kc hvp[b][kc][m][d]) ----
__global__ __launch_bounds__(256) void k_out(const float* __restrict__ h,
                                             const float* __restrict__ wo,
                                             const float* __restrict__ hvp,
                                             float* __restrict__ out0) {
    int bx = blockIdx.x;                           // 128: b(4) x mt(32)
    int b = bx >> 5, mt = bx & 31;
    int m0 = mt * 32;
    int tid = threadIdx.x;
    __shared__ float hvL[32][33];
    for (int i = tid; i < 1024; i += 256) {
        int mm = i >> 5, d = i & 31;
        float s = 0.f;
#pragma unroll
        for (int kc = 0; kc < NKC; kc++)
            s += hvp[(((size_t)(b * NKC + kc)) << 15) + (size_t)(m0 + mm) * HID + d]; // coalesced
        hvL[mm][d] = s;
    }
    __syncthreads();
    for (int i = tid; i < CC * 32; i += 256) {
        int c = i >> 5, mm = i & 31;
        float v = h[(size_t)(b * CC + c) * NN + m0 + mm];
#pragma unroll
        for (int d = 0; d < HID; d++) v += wo[c * HID + d] * hvL[mm][d];
        out0[(size_t)(b * CC + c) * NN + m0 + mm] = v;
    }
}

extern "C" void kernel_launch(void* const* d_in, const int* in_sizes, int n_in,
                              void* d_out, int out_size, void* d_ws, size_t ws_size,
                              hipStream_t stream) {
    const float* H   = (const float*)d_in[0];
    const float* h   = (const float*)d_in[1];
    const float* wq  = (const float*)d_in[2];
    const float* wkv = (const float*)d_in[3];
    const float* wo  = (const float*)d_in[4];

    float* out0 = (float*)d_out;                       // [4,64,32,32]
    float* att  = out0 + (size_t)BB * CC * NN;         // [4,8192,1024]

    ushort_t* hqHI  = (ushort_t*)d_ws;                 // 131072
    ushort_t* hqLO  = hqHI  + 131072;                  // 131072
    ushort_t* hkTH0 = hqLO  + 131072;                  // 524288
    ushort_t* hkTH1 = hkTH0 + 524288;                  // 524288
    ushort_t* hkTL0 = hkTH1 + 524288;                  // 524288
    ushort_t* hkTL1 = hkTL0 + 524288;                  // 524288
    ushort_t* hkDB  = hkTL1 + 524288;                  // 1048576
    float* psum = (float*)(hkDB + 1048576);            // 65536
    float* hvp  = psum + 65536;                        // 2097152  (~15.5 MB total)

    k_pre <<<272, 256, 0, stream>>>(H, h, wq, wkv, hqHI, hqLO,
                                    hkTH0, hkTH1, hkTL0, hkTL1, hkDB);
    k_psum<<<512, 512, 0, stream>>>(hqHI, hqLO, hkTH0, hkTH1, hkTL0, hkTL1, psum);
    k_att2<<<512, 512, 0, stream>>>(hqHI, hqLO, hkTH0, hkTH1, hkTL0, hkTL1, hkDB,
                                    psum, att, hvp);
    k_out <<<128, 256, 0, stream>>>(h, wo, hvp, out0);
}

// Round 9
// 93.846 us; speedup vs baseline: 4.8992x; 1.1225x over previous
//
#include <hip/hip_runtime.h>

typedef short bf16x8 __attribute__((ext_vector_type(8)));
typedef float f32x4  __attribute__((ext_vector_type(4)));
typedef unsigned short ushort_t;

#define HID 32
#define CC  64
#define TT  8
#define NN  1024
#define BB  4
#define KTOT 8192
#define NKC_A 16               // k-chunks for k_att2; KCHUNK_A=512 (single t per chunk)
#define KCHUNK_A (KTOT/NKC_A)  // 512
#define NKC_P 32               // k-chunks for k_psum; KCHUNK_P=256
#define KCHUNK_P (KTOT/NKC_P)  // 256

// f32 -> bf16 (RNE)
__device__ __forceinline__ ushort_t f2b(float x) {
    unsigned int u = __float_as_uint(x);
    return (ushort_t)((u + 0x7fffu + ((u >> 16) & 1u)) >> 16);
}
__device__ __forceinline__ float b2f(ushort_t u) {
    return __uint_as_float((unsigned int)u << 16);
}

// --- K1 fused: blocks 0..255 -> hkT planes + hkDB;  blocks 256..271 -> hq hi/lo ---
__global__ __launch_bounds__(256) void k_pre(const float* __restrict__ H,
                                             const float* __restrict__ h,
                                             const float* __restrict__ wq,
                                             const float* __restrict__ wkv,
                                             ushort_t* __restrict__ hqHI,
                                             ushort_t* __restrict__ hqLO,
                                             ushort_t* __restrict__ hkTH0,
                                             ushort_t* __restrict__ hkTH1,
                                             ushort_t* __restrict__ hkTL0,
                                             ushort_t* __restrict__ hkTL1,
                                             ushort_t* __restrict__ hkDB) {
    int bx = blockIdx.x;
    if (bx < 256) {
        // H_kv: hi/lo k-major planes (16-wide) + d-major bf16
        int gid = bx * 256 + threadIdx.x;          // 0..65535
        int dg = gid >> 15;                        // block-uniform d-half
        int rest = gid & 32767;
        int b = rest >> 13, tn = rest & 8191;
        int d0 = dg << 4;
        float acc[16];
#pragma unroll
        for (int d = 0; d < 16; d++) acc[d] = 0.f;
        const float* Hb = H + (size_t)(b * CC) * KTOT + tn;
        const float* wb = wkv + d0 * CC;
#pragma unroll 8
        for (int c = 0; c < CC; c++) {
            float v = Hb[(size_t)c * KTOT];        // coalesced
#pragma unroll
            for (int d = 0; d < 16; d++) acc[d] += wb[d * CC + c] * v;  // uniform -> s_load
        }
        ushort_t thi[16], tlo[16];
#pragma unroll
        for (int d = 0; d < 16; d++) {
            ushort_t hi = f2b(acc[d]);
            thi[d] = hi;
            tlo[d] = f2b(acc[d] - b2f(hi));
        }
        size_t po = ((size_t)b * KTOT + tn) * 16;
        bf16x8* ohi = (bf16x8*)((dg ? hkTH1 : hkTH0) + po);
        bf16x8* olo = (bf16x8*)((dg ? hkTL1 : hkTL0) + po);
#pragma unroll
        for (int v8 = 0; v8 < 2; v8++) {
            bf16x8 a, l;
#pragma unroll
            for (int j = 0; j < 8; j++) { a[j] = (short)thi[v8*8+j]; l[j] = (short)tlo[v8*8+j]; }
            ohi[v8] = a; olo[v8] = l;
        }
#pragma unroll
        for (int d = 0; d < 16; d++)
            hkDB[((size_t)(b * HID) + d0 + d) * KTOT + tn] = thi[d];   // coalesced per d
    } else {
        // h_q hi/lo, layout [b*N+n][32]
        int gid = (bx - 256) * 256 + threadIdx.x;  // 0..4095
        int b = gid >> 10;
        float acc[HID];
#pragma unroll
        for (int d = 0; d < HID; d++) acc[d] = 0.f;
        const float* hb = h + (size_t)(b * CC) * NN + (gid & 1023);
#pragma unroll 4
        for (int c = 0; c < CC; c++) {
            float v = hb[c * NN];                  // coalesced
#pragma unroll
            for (int d = 0; d < HID; d++) acc[d] += wq[d * CC + c] * v;
        }
        bf16x8* ohi = (bf16x8*)(hqHI + (size_t)gid * HID);
        bf16x8* olo = (bf16x8*)(hqLO + (size_t)gid * HID);
#pragma unroll
        for (int v8 = 0; v8 < 4; v8++) {
            bf16x8 thi, tlo;
#pragma unroll
            for (int j = 0; j < 8; j++) {
                float x = acc[v8 * 8 + j];
                ushort_t hi = f2b(x);
                thi[j] = (short)hi;
                tlo[j] = (short)f2b(x - b2f(hi));
            }
            ohi[v8] = thi; olo[v8] = tlo;
        }
    }
}

// ---- Pass A: psum[b][kc][m] over 256-row chunks. 1024 blocks, 8 waves/SIMD target ----
__global__ __launch_bounds__(512, 8) void k_psum(const ushort_t* __restrict__ hqHI,
                                                 const ushort_t* __restrict__ hqLO,
                                                 const ushort_t* __restrict__ hkTH0,
                                                 const ushort_t* __restrict__ hkTH1,
                                                 const ushort_t* __restrict__ hkTL0,
                                                 const ushort_t* __restrict__ hkTL1,
                                                 float* __restrict__ psum) {
    int bx = blockIdx.x;                           // 1024: b(4) x mt(8) x kc(32)
    int b = bx >> 8, mt = (bx >> 5) & 7, kc = bx & 31;
    int wave = threadIdx.x >> 6, lane = threadIdx.x & 63;
    int g = lane >> 4, c = lane & 15;
    int m = mt * 128 + wave * 16 + c;
    int t = kc >> 2;
    int nb0 = (kc & 3) << 8;                       // chunk covers n in [nb0, nb0+256)

    // B frag: key column hkT[t,m], hi/lo, plane g>>1, offset (g&1)*8
    size_t bqo = ((size_t)b * KTOT + t * NN + m) * 16 + (g & 1) * 8;
    bf16x8 bqh = *(const bf16x8*)(((g >> 1) ? hkTH1 : hkTH0) + bqo);
    bf16x8 bql = *(const bf16x8*)(((g >> 1) ? hkTL1 : hkTL0) + bqo);

    const ushort_t* qhi = hqHI + ((size_t)(b << 10)) * HID;
    const ushort_t* qlo = hqLO + ((size_t)(b << 10)) * HID;

    float csum0 = 0.f, csum1 = 0.f;
    for (int s16 = 0; s16 < KCHUNK_P / 16; s16 += 2) {  // 8 iters, 2 tiles each
        int nbA = nb0 + s16 * 16;
        int nbB = nbA + 16;
        size_t aoA = (size_t)(nbA + c) * HID + 8 * g;
        size_t aoB = (size_t)(nbB + c) * HID + 8 * g;
        bf16x8 ahA = *(const bf16x8*)(qhi + aoA);
        bf16x8 alA = *(const bf16x8*)(qlo + aoA);
        bf16x8 ahB = *(const bf16x8*)(qhi + aoB);
        bf16x8 alB = *(const bf16x8*)(qlo + aoB);
        f32x4 svA = __builtin_amdgcn_mfma_f32_16x16x32_bf16(ahA, bql, (f32x4){0.f,0.f,0.f,0.f}, 0, 0, 0);
        f32x4 svB = __builtin_amdgcn_mfma_f32_16x16x32_bf16(ahB, bql, (f32x4){0.f,0.f,0.f,0.f}, 0, 0, 0);
        svA = __builtin_amdgcn_mfma_f32_16x16x32_bf16(alA, bqh, svA, 0, 0, 0);
        svB = __builtin_amdgcn_mfma_f32_16x16x32_bf16(alB, bqh, svB, 0, 0, 0);
        svA = __builtin_amdgcn_mfma_f32_16x16x32_bf16(ahA, bqh, svA, 0, 0, 0);
        svB = __builtin_amdgcn_mfma_f32_16x16x32_bf16(ahB, bqh, svB, 0, 0, 0);
        int nrowA = nbA + 4 * g;                   // D row = query n
        int nrowB = nbB + 4 * g;
#pragma unroll
        for (int r = 0; r < 4; r++) {
            float xA = (nrowA + r == m) ? 0.f : svA[r];
            float xB = (nrowB + r == m) ? 0.f : svB[r];
            csum0 += __expf(xA);
            csum1 += __expf(xB);
        }
    }
    float csum = csum0 + csum1;
    csum += __shfl_xor(csum, 16);
    csum += __shfl_xor(csum, 32);
    if (lane < 16)
        psum[(((size_t)(b * NKC_P + kc)) << 10) + mt * 128 + wave * 16 + lane] = csum;
}

// ---- Pass B: S^T orientation (A=key m-tile, B=query n-tile) -> dwordx4 att stores ----
__global__ __launch_bounds__(512, 4) void k_att2(const ushort_t* __restrict__ hqHI,
                                                 const ushort_t* __restrict__ hqLO,
                                                 const ushort_t* __restrict__ hkTH0,
                                                 const ushort_t* __restrict__ hkTH1,
                                                 const ushort_t* __restrict__ hkTL0,
                                                 const ushort_t* __restrict__ hkTL1,
                                                 const ushort_t* __restrict__ hkDB,
                                                 const float* __restrict__ psum,
                                                 float* __restrict__ att,
                                                 float* __restrict__ hvp) {
    int bx = blockIdx.x;                           // 512: b(4) x mt(8) x kc(16)
    int b = bx >> 7, mt = (bx >> 4) & 7, kc = bx & 15;
    int wave = threadIdx.x >> 6, lane = threadIdx.x & 63;
    int g = lane >> 4, c = lane & 15;
    int mb = mt * 128 + wave * 16;                 // wave's 16-wide m-tile
    int t = kc >> 1;
    int nb0 = (kc & 1) << 9;

    // denominators for this lane's 4 m's (m = mb + 4g + r)
    f32x4 gs = {0.f, 0.f, 0.f, 0.f};
#pragma unroll
    for (int j = 0; j < NKC_P; j++)
        gs += *(const f32x4*)(psum + (((size_t)(b * NKC_P + j)) << 10) + mb + 4 * g);
    f32x4 vinv;
#pragma unroll
    for (int r = 0; r < 4; r++) vinv[r] = 1.0f / gs[r];

    // A frag (loop-invariant): key[m = mb + c][d = 8g+j], hi/lo
    size_t ako = ((size_t)b * KTOT + t * NN + (mb + c)) * 16 + (g & 1) * 8;
    bf16x8 akh = *(const bf16x8*)(((g >> 1) ? hkTH1 : hkTH0) + ako);
    bf16x8 akl = *(const bf16x8*)(((g >> 1) ? hkTL1 : hkTL0) + ako);

    const ushort_t* qhi = hqHI + ((size_t)(b << 10)) * HID;
    const ushort_t* qlo = hqLO + ((size_t)(b << 10)) * HID;
    const ushort_t* vb0 = hkDB + (size_t)(b * HID + c) * KTOT;
    const ushort_t* vb1 = hkDB + (size_t)(b * HID + 16 + c) * KTOT;
    float* attb = att + (size_t)b * KTOT * NN;

    // per-wave P-transpose tile: PT[m-local 16][k-local 32 pad->40]
    __shared__ __align__(16) ushort_t PT[8][16][40];
    ushort_t (*pt)[40] = PT[wave];

    f32x4 acc0 = {0.f,0.f,0.f,0.f}, acc1 = {0.f,0.f,0.f,0.f};

    for (int ks = 0; ks < KCHUNK_A / 32; ks++) {   // 16 iters, 32 k each
        int k0 = kc * KCHUNK_A + ks * 32;
#pragma unroll
        for (int half = 0; half < 2; half++) {
            int nb = nb0 + ks * 32 + half * 16;    // n-tile base
            size_t qo = (size_t)(nb + c) * HID + 8 * g;
            bf16x8 qh = *(const bf16x8*)(qhi + qo);
            bf16x8 ql = *(const bf16x8*)(qlo + qo);
            // S^T[m][n] = sum_d key[m,d]*q[n,d]  (hi*lo + lo*hi + hi*hi)
            f32x4 sv = __builtin_amdgcn_mfma_f32_16x16x32_bf16(akh, ql, (f32x4){0.f,0.f,0.f,0.f}, 0, 0, 0);
            sv = __builtin_amdgcn_mfma_f32_16x16x32_bf16(akl, qh, sv, 0, 0, 0);
            sv = __builtin_amdgcn_mfma_f32_16x16x32_bf16(akh, qh, sv, 0, 0, 0);
            int n = nb + c;                        // this lane's att row (k = t*NN + n)
            float e0, e1, e2, e3;
            {
                float x0 = (n == mb + 4 * g + 0) ? 0.f : sv[0];
                float x1 = (n == mb + 4 * g + 1) ? 0.f : sv[1];
                float x2 = (n == mb + 4 * g + 2) ? 0.f : sv[2];
                float x3 = (n == mb + 4 * g + 3) ? 0.f : sv[3];
                e0 = __expf(x0) * vinv[0];
                e1 = __expf(x1) * vinv[1];
                e2 = __expf(x2) * vinv[2];
                e3 = __expf(x3) * vinv[3];
            }
            f32x4 ev; ev[0] = e0; ev[1] = e1; ev[2] = e2; ev[3] = e3;
            __builtin_nontemporal_store(ev,
                (f32x4*)(attb + (size_t)(t * NN + n) * NN + mb + 4 * g));  // 16B/lane stream
            // PT[m-local][k-local]: m-local = 4g+r, k-local = half*16 + c
            int kl = half * 16 + c;
            pt[4 * g + 0][kl] = f2b(e0);
            pt[4 * g + 1][kl] = f2b(e1);
            pt[4 * g + 2][kl] = f2b(e2);
            pt[4 * g + 3][kl] = f2b(e3);
        }
        // GEMM2: hv[m,d] += sum_k P[m,k] * V[k,d]
        bf16x8 pa = *(const bf16x8*)&pt[c][8 * g];        // A2[m=c][k=8g+j]
        bf16x8 v0 = *(const bf16x8*)(vb0 + k0 + 8 * g);   // B2[k][d=c]
        bf16x8 v1 = *(const bf16x8*)(vb1 + k0 + 8 * g);   // B2[k][d=16+c]
        acc0 = __builtin_amdgcn_mfma_f32_16x16x32_bf16(pa, v0, acc0, 0, 0, 0);
        acc1 = __builtin_amdgcn_mfma_f32_16x16x32_bf16(pa, v1, acc1, 0, 0, 0);
    }
    // hvp[b][kc][m][d]; D2 row = m-local (4g+r), col = d (c / 16+c)
    float* o = hvp + ((((size_t)(b * NKC_A + kc)) << 10) + mb) * HID;
#pragma unroll
    for (int r = 0; r < 4; r++) {
        o[(size_t)(4 * g + r) * HID + c]      = acc0[r];
        o[(size_t)(4 * g + r) * HID + 16 + c] = acc1[r];
    }
}

// ---- out0[b,c,m] = h[b,c,m] + sum_d w_o[c,d] * (sum_kc hvp[b][kc][m][d]) ----
__global__ __launch_bounds__(256) void k_out(const float* __restrict__ h,
                                             const float* __restrict__ wo,
                                             const float* __restrict__ hvp,
                                             float* __restrict__ out0) {
    int bx = blockIdx.x;                           // 256: b(4) x mt(64)
    int b = bx >> 6, mt = bx & 63;
    int m0 = mt * 16;
    int tid = threadIdx.x;
    __shared__ float hvL[16][33];
    for (int i = tid; i < 512; i += 256) {
        int mm = i >> 5, d = i & 31;
        float s = 0.f;
#pragma unroll
        for (int kc = 0; kc < NKC_A; kc++)
            s += hvp[(((size_t)(b * NKC_A + kc)) << 15) + (size_t)(m0 + mm) * HID + d]; // coalesced
        hvL[mm][d] = s;
    }
    __syncthreads();
    for (int i = tid; i < CC * 16; i += 256) {
        int c = i >> 4, mm = i & 15;
        float v = h[(size_t)(b * CC + c) * NN + m0 + mm];
#pragma unroll
        for (int d = 0; d < HID; d++) v += wo[c * HID + d] * hvL[mm][d];
        out0[(size_t)(b * CC + c) * NN + m0 + mm] = v;
    }
}

extern "C" void kernel_launch(void* const* d_in, const int* in_sizes, int n_in,
                              void* d_out, int out_size, void* d_ws, size_t ws_size,
                              hipStream_t stream) {
    const float* H   = (const float*)d_in[0];
    const float* h   = (const float*)d_in[1];
    const float* wq  = (const float*)d_in[2];
    const float* wkv = (const float*)d_in[3];
    const float* wo  = (const float*)d_in[4];

    float* out0 = (float*)d_out;                       // [4,64,32,32]
    float* att  = out0 + (size_t)BB * CC * NN;         // [4,8192,1024]

    ushort_t* hqHI  = (ushort_t*)d_ws;                 // 131072
    ushort_t* hqLO  = hqHI  + 131072;                  // 131072
    ushort_t* hkTH0 = hqLO  + 131072;                  // 524288
    ushort_t* hkTH1 = hkTH0 + 524288;                  // 524288
    ushort_t* hkTL0 = hkTH1 + 524288;                  // 524288
    ushort_t* hkTL1 = hkTL0 + 524288;                  // 524288
    ushort_t* hkDB  = hkTL1 + 524288;                  // 1048576
    float* psum = (float*)(hkDB + 1048576);            // 131072 (32 chunks)
    float* hvp  = psum + 131072;                       // 2097152  (~16 MB total)

    k_pre <<<272,  256, 0, stream>>>(H, h, wq, wkv, hqHI, hqLO,
                                     hkTH0, hkTH1, hkTL0, hkTL1, hkDB);
    k_psum<<<1024, 512, 0, stream>>>(hqHI, hqLO, hkTH0, hkTH1, hkTL0, hkTL1, psum);
    k_att2<<<512,  512, 0, stream>>>(hqHI, hqLO, hkTH0, hkTH1, hkTL0, hkTL1, hkDB,
                                     psum, att, hvp);
    k_out <<<256,  256, 0, stream>>>(h, wo, hvp, out0);
}